// Round 8
// baseline (29876.212 us; speedup 1.0000x reference)
//
#include <hip/hip_runtime.h>

// Problem constants (fixed by reference setup)
#define NN     10000      // variable nodes
#define NF     80000      // factors
#define NE     160000     // directed edges per direction
#define SDIM   64         // state dim
#define HMDIM  128        // hidden (message MLP)
#define HRDIM  128        // hidden (readout)
#define KIN    136        // 2*S + 8
#define NSTEPS 5

static_assert(NE % 64 == 0, "edge grid exact");
static_assert(NF % 64 == 0, "factor grid exact");

// ---------- helpers ----------
static __device__ __forceinline__ float sigm(float x) {
    x = fminf(fmaxf(x, -30.f), 30.f);
    return 1.f / (1.f + __expf(-x));
}
static __device__ __forceinline__ float tanh_f(float x) {
    x = fminf(fmaxf(x, -15.f), 15.f);
    float t = __expf(2.f * x);
    return (t - 1.f) / (t + 1.f);
}

__global__ void k_zero(float* __restrict__ p, int n) {
    int i = blockIdx.x * blockDim.x + threadIdx.x;
    int stride = gridDim.x * blockDim.x;
    for (; i < n; i += stride) p[i] = 0.f;
}

// ---------- fac->var: fused edge MLP + atomic scatter into nm_var ----------
// One lane = one edge. x = [fac_h[r] (64), var_h[c] (64), feat[r] (4),
// feat[c] (4)] -> 128 relu -> 128 relu -> 64, atomically accumulated into
// nm_var[c]. Weights wave-uniform -> scalar loads; hidden activations
// stage through a per-lane-private f32 LDS column (exact, no barriers).
__global__ __launch_bounds__(64)
void k_edge_scatter(const float* __restrict__ fac_h,   // f32 [NF,64]
                    const float* __restrict__ var_h,   // f32 [NN,64]
                    const int* __restrict__ rows, const int* __restrict__ cols,
                    const float* __restrict__ feat,    // f32 [NE,4]
                    const float* __restrict__ w1, const float* __restrict__ b1,
                    const float* __restrict__ w2, const float* __restrict__ b2,
                    const float* __restrict__ w3, const float* __restrict__ b3,
                    float* __restrict__ nmv)
{
    __shared__ float hbuf[HMDIM][64];             // [j][tid], 32 KB f32
    const int tid = threadIdx.x;
    const int e = blockIdx.x * 64 + tid;          // grid exact: NE/64 blocks
    const int r = rows[e];                        // factor index < NF
    const int c = cols[e];                        // node index   < NN

    float xr[KIN];
    {
        const float4* pr = (const float4*)(fac_h + (size_t)r * SDIM);
        const float4* pc = (const float4*)(var_h + (size_t)c * SDIM);
        #pragma unroll
        for (int i = 0; i < 16; ++i) {
            float4 t = pr[i];
            xr[4*i+0] = t.x; xr[4*i+1] = t.y; xr[4*i+2] = t.z; xr[4*i+3] = t.w;
        }
        #pragma unroll
        for (int i = 0; i < 16; ++i) {
            float4 t = pc[i];
            xr[64+4*i+0] = t.x; xr[64+4*i+1] = t.y; xr[64+4*i+2] = t.z; xr[64+4*i+3] = t.w;
        }
        float4 fr = *(const float4*)(feat + (size_t)r * 4);
        float4 fc = *(const float4*)(feat + (size_t)c * 4);
        xr[128] = fr.x; xr[129] = fr.y; xr[130] = fr.z; xr[131] = fr.w;
        xr[132] = fc.x; xr[133] = fc.y; xr[134] = fc.z; xr[135] = fc.w;
    }

    // layer 1: KIN -> 128, relu (f32 into LDS)
    for (int jc = 0; jc < HMDIM; jc += 8) {
        float acc[8];
        #pragma unroll
        for (int jj = 0; jj < 8; ++jj) acc[jj] = b1[jc + jj];
        #pragma unroll
        for (int k = 0; k < KIN; ++k) {
            float xk = xr[k];
            #pragma unroll
            for (int jj = 0; jj < 8; ++jj)
                acc[jj] = fmaf(w1[(jc + jj) * KIN + k], xk, acc[jj]);
        }
        #pragma unroll
        for (int jj = 0; jj < 8; ++jj)
            hbuf[jc + jj][tid] = fmaxf(acc[jj], 0.f);
    }
    // layer 2: 128 -> 128, relu
    #pragma unroll
    for (int k = 0; k < HMDIM; ++k) xr[k] = hbuf[k][tid];
    for (int jc = 0; jc < HMDIM; jc += 8) {
        float acc[8];
        #pragma unroll
        for (int jj = 0; jj < 8; ++jj) acc[jj] = b2[jc + jj];
        #pragma unroll
        for (int k = 0; k < HMDIM; ++k) {
            float xk = xr[k];
            #pragma unroll
            for (int jj = 0; jj < 8; ++jj)
                acc[jj] = fmaf(w2[(jc + jj) * HMDIM + k], xk, acc[jj]);
        }
        #pragma unroll
        for (int jj = 0; jj < 8; ++jj)
            hbuf[jc + jj][tid] = fmaxf(acc[jj], 0.f);
    }
    // layer 3: 128 -> 64 (linear), atomic accumulate into nm_var[c]
    #pragma unroll
    for (int k = 0; k < HMDIM; ++k) xr[k] = hbuf[k][tid];
    float* no = nmv + (size_t)c * 64;
    for (int jc = 0; jc < 64; jc += 8) {
        float acc[8];
        #pragma unroll
        for (int jj = 0; jj < 8; ++jj) acc[jj] = b3[jc + jj];
        #pragma unroll
        for (int k = 0; k < HMDIM; ++k) {
            float xk = xr[k];
            #pragma unroll
            for (int jj = 0; jj < 8; ++jj)
                acc[jj] = fmaf(w3[(jc + jj) * HMDIM + k], xk, acc[jj]);
        }
        #pragma unroll
        for (int jj = 0; jj < 8; ++jj) atomicAdd(&no[jc + jj], acc[jj]);
    }
}

// ---------- GRU for variable nodes (reads nm_var, zeroes it for next step) ----------
__global__ __launch_bounds__(256)
void k_var_gru(float* __restrict__ nmv,
               const float* __restrict__ wih, const float* __restrict__ whh,
               const float* __restrict__ bih, const float* __restrict__ bhh,
               float* __restrict__ hst)
{
    int n0 = blockIdx.x * 256 + threadIdx.x;
    int n = n0 < NN ? n0 : NN - 1;                 // clamp keeps CF uniform
    float nm[SDIM], h[SDIM];
    {
        const float4* m4 = (const float4*)(nmv + (size_t)n * 64);
        const float4* h4 = (const float4*)(hst + (size_t)n * 64);
        #pragma unroll
        for (int q = 0; q < 16; ++q) {
            float4 t = m4[q];
            nm[4*q+0] = t.x; nm[4*q+1] = t.y; nm[4*q+2] = t.z; nm[4*q+3] = t.w;
        }
        #pragma unroll
        for (int q = 0; q < 16; ++q) {
            float4 t = h4[q];
            h[4*q+0] = t.x; h[4*q+1] = t.y; h[4*q+2] = t.z; h[4*q+3] = t.w;
        }
    }
    float hn[SDIM];
    for (int jc = 0; jc < SDIM; jc += 4) {
        float air[4], aiz[4], ain[4], ahr[4], ahz[4], ahn[4];
        #pragma unroll
        for (int jj = 0; jj < 4; ++jj) {
            int j = jc + jj;
            air[jj] = bih[j];       aiz[jj] = bih[64 + j];  ain[jj] = bih[128 + j];
            ahr[jj] = bhh[j];       ahz[jj] = bhh[64 + j];  ahn[jj] = bhh[128 + j];
        }
        #pragma unroll
        for (int k = 0; k < SDIM; ++k) {
            float xk = nm[k], hk = h[k];
            #pragma unroll
            for (int jj = 0; jj < 4; ++jj) {
                int j = jc + jj;
                air[jj] = fmaf(wih[j * 64 + k],         xk, air[jj]);
                aiz[jj] = fmaf(wih[(64 + j) * 64 + k],  xk, aiz[jj]);
                ain[jj] = fmaf(wih[(128 + j) * 64 + k], xk, ain[jj]);
                ahr[jj] = fmaf(whh[j * 64 + k],         hk, ahr[jj]);
                ahz[jj] = fmaf(whh[(64 + j) * 64 + k],  hk, ahz[jj]);
                ahn[jj] = fmaf(whh[(128 + j) * 64 + k], hk, ahn[jj]);
            }
        }
        #pragma unroll
        for (int jj = 0; jj < 4; ++jj) {
            float r = sigm(air[jj] + ahr[jj]);
            float z = sigm(aiz[jj] + ahz[jj]);
            float t = tanh_f(ain[jj] + r * ahn[jj]);
            hn[jc + jj] = (1.f - z) * t + z * h[jc + jj];
        }
    }
    if (n0 < NN) {
        float4* ho = (float4*)(hst + (size_t)n * 64);
        float4* mo = (float4*)(nmv + (size_t)n * 64);
        #pragma unroll
        for (int q = 0; q < 16; ++q) {
            ho[q] = make_float4(hn[4*q+0], hn[4*q+1], hn[4*q+2], hn[4*q+3]);
            mo[q] = make_float4(0.f, 0.f, 0.f, 0.f);   // ready for next step
        }
    }
}

// ---------- var->fac: fully fused (2 edge MLPs + pair reduce + GRU) per factor ----------
// One lane = one factor f; edges 2f, 2f+1 have col==f structurally
// (var2fac_col = repeat(arange(F), 2)).
__global__ __launch_bounds__(64)
void k_fac_fused(const float* __restrict__ var_h, float* __restrict__ fac_h,
                 const int* __restrict__ rows,      // v2f_row (node endpoints)
                 const float* __restrict__ feat,    // f32 [NE,4]
                 const float* __restrict__ w1, const float* __restrict__ b1,
                 const float* __restrict__ w2, const float* __restrict__ b2,
                 const float* __restrict__ w3, const float* __restrict__ b3,
                 const float* __restrict__ wih, const float* __restrict__ whh,
                 const float* __restrict__ bih, const float* __restrict__ bhh)
{
    __shared__ float hbuf[HMDIM][64];             // [j][tid], 32 KB f32
    const int tid = threadIdx.x;
    const int f = blockIdx.x * 64 + tid;          // grid exact: NF/64 blocks

    float h[SDIM];
    {
        const float4* h4 = (const float4*)(fac_h + (size_t)f * SDIM);
        #pragma unroll
        for (int q = 0; q < 16; ++q) {
            float4 t = h4[q];
            h[4*q+0] = t.x; h[4*q+1] = t.y; h[4*q+2] = t.z; h[4*q+3] = t.w;
        }
    }
    float4 fcf = *(const float4*)(feat + (size_t)f * 4);

    float nm[SDIM];
    #pragma unroll
    for (int k = 0; k < SDIM; ++k) nm[k] = 0.f;

    for (int ei = 0; ei < 2; ++ei) {
        const int e = 2 * f + ei;
        const int r = rows[e];                    // node index < NN
        float xr[KIN];
        {
            const float4* pr = (const float4*)(var_h + (size_t)r * SDIM);
            #pragma unroll
            for (int i = 0; i < 16; ++i) {
                float4 t = pr[i];
                xr[4*i+0] = t.x; xr[4*i+1] = t.y; xr[4*i+2] = t.z; xr[4*i+3] = t.w;
            }
            #pragma unroll
            for (int k = 0; k < SDIM; ++k) xr[64 + k] = h[k];
            float4 fr = *(const float4*)(feat + (size_t)r * 4);
            xr[128] = fr.x; xr[129] = fr.y; xr[130] = fr.z; xr[131] = fr.w;
            xr[132] = fcf.x; xr[133] = fcf.y; xr[134] = fcf.z; xr[135] = fcf.w;
        }
        // layer 1
        for (int jc = 0; jc < HMDIM; jc += 8) {
            float acc[8];
            #pragma unroll
            for (int jj = 0; jj < 8; ++jj) acc[jj] = b1[jc + jj];
            #pragma unroll
            for (int k = 0; k < KIN; ++k) {
                float xk = xr[k];
                #pragma unroll
                for (int jj = 0; jj < 8; ++jj)
                    acc[jj] = fmaf(w1[(jc + jj) * KIN + k], xk, acc[jj]);
            }
            #pragma unroll
            for (int jj = 0; jj < 8; ++jj)
                hbuf[jc + jj][tid] = fmaxf(acc[jj], 0.f);
        }
        // layer 2
        #pragma unroll
        for (int k = 0; k < HMDIM; ++k) xr[k] = hbuf[k][tid];
        for (int jc = 0; jc < HMDIM; jc += 8) {
            float acc[8];
            #pragma unroll
            for (int jj = 0; jj < 8; ++jj) acc[jj] = b2[jc + jj];
            #pragma unroll
            for (int k = 0; k < HMDIM; ++k) {
                float xk = xr[k];
                #pragma unroll
                for (int jj = 0; jj < 8; ++jj)
                    acc[jj] = fmaf(w2[(jc + jj) * HMDIM + k], xk, acc[jj]);
            }
            #pragma unroll
            for (int jj = 0; jj < 8; ++jj)
                hbuf[jc + jj][tid] = fmaxf(acc[jj], 0.f);
        }
        // layer 3 -> accumulate into nm
        #pragma unroll
        for (int k = 0; k < HMDIM; ++k) xr[k] = hbuf[k][tid];
        for (int jc = 0; jc < 64; jc += 8) {
            float acc[8];
            #pragma unroll
            for (int jj = 0; jj < 8; ++jj) acc[jj] = b3[jc + jj];
            #pragma unroll
            for (int k = 0; k < HMDIM; ++k) {
                float xk = xr[k];
                #pragma unroll
                for (int jj = 0; jj < 8; ++jj)
                    acc[jj] = fmaf(w3[(jc + jj) * HMDIM + k], xk, acc[jj]);
            }
            #pragma unroll
            for (int jj = 0; jj < 8; ++jj) nm[jc + jj] += acc[jj];
        }
    }

    // GRU update of fac_h[f] in place
    for (int jc = 0; jc < SDIM; jc += 4) {
        float air[4], aiz[4], ain[4], ahr[4], ahz[4], ahn[4];
        #pragma unroll
        for (int jj = 0; jj < 4; ++jj) {
            int j = jc + jj;
            air[jj] = bih[j];       aiz[jj] = bih[64 + j];  ain[jj] = bih[128 + j];
            ahr[jj] = bhh[j];       ahz[jj] = bhh[64 + j];  ahn[jj] = bhh[128 + j];
        }
        #pragma unroll
        for (int k = 0; k < SDIM; ++k) {
            float xk = nm[k], hk = h[k];
            #pragma unroll
            for (int jj = 0; jj < 4; ++jj) {
                int j = jc + jj;
                air[jj] = fmaf(wih[j * 64 + k],         xk, air[jj]);
                aiz[jj] = fmaf(wih[(64 + j) * 64 + k],  xk, aiz[jj]);
                ain[jj] = fmaf(wih[(128 + j) * 64 + k], xk, ain[jj]);
                ahr[jj] = fmaf(whh[j * 64 + k],         hk, ahr[jj]);
                ahz[jj] = fmaf(whh[(64 + j) * 64 + k],  hk, ahz[jj]);
                ahn[jj] = fmaf(whh[(128 + j) * 64 + k], hk, ahn[jj]);
            }
        }
        #pragma unroll
        for (int jj = 0; jj < 4; ++jj) {
            float r = sigm(air[jj] + ahr[jj]);
            float z = sigm(aiz[jj] + ahz[jj]);
            float t = tanh_f(ain[jj] + r * ahn[jj]);
            fac_h[(size_t)f * 64 + jc + jj] = (1.f - z) * t + z * h[jc + jj];
        }
    }
}

// ---------- readout MLP + 2-class softmax -> f32 output ----------
__global__ __launch_bounds__(256)
void k_readout(const float* __restrict__ vh,
               const float* __restrict__ w1, const float* __restrict__ b1,
               const float* __restrict__ w2, const float* __restrict__ b2,
               const float* __restrict__ w3, const float* __restrict__ b3,
               float* __restrict__ out)
{
    int n0 = blockIdx.x * 256 + threadIdx.x;
    int n = n0 < NN ? n0 : NN - 1;
    float x[SDIM];
    {
        const float4* h4 = (const float4*)(vh + (size_t)n * 64);
        #pragma unroll
        for (int q = 0; q < 16; ++q) {
            float4 t = h4[q];
            x[4*q+0] = t.x; x[4*q+1] = t.y; x[4*q+2] = t.z; x[4*q+3] = t.w;
        }
    }
    float h1[HRDIM];
    for (int jc = 0; jc < HRDIM; jc += 8) {
        float acc[8];
        #pragma unroll
        for (int jj = 0; jj < 8; ++jj) acc[jj] = b1[jc + jj];
        #pragma unroll
        for (int k = 0; k < SDIM; ++k) {
            float xk = x[k];
            #pragma unroll
            for (int jj = 0; jj < 8; ++jj)
                acc[jj] = fmaf(w1[(jc + jj) * SDIM + k], xk, acc[jj]);
        }
        #pragma unroll
        for (int jj = 0; jj < 8; ++jj) h1[jc + jj] = fmaxf(acc[jj], 0.f);
    }
    float l0 = b3[0], l1 = b3[1];
    for (int jc = 0; jc < HRDIM; jc += 8) {
        float acc[8];
        #pragma unroll
        for (int jj = 0; jj < 8; ++jj) acc[jj] = b2[jc + jj];
        #pragma unroll
        for (int k = 0; k < HRDIM; ++k) {
            float xk = h1[k];
            #pragma unroll
            for (int jj = 0; jj < 8; ++jj)
                acc[jj] = fmaf(w2[(jc + jj) * HRDIM + k], xk, acc[jj]);
        }
        #pragma unroll
        for (int jj = 0; jj < 8; ++jj) {
            float v = fmaxf(acc[jj], 0.f);
            l0 = fmaf(w3[jc + jj], v, l0);
            l1 = fmaf(w3[HRDIM + jc + jj], v, l1);
        }
    }
    if (n0 < NN) {
        float mx = fmaxf(l0, l1);
        float e0 = __expf(l0 - mx), e1 = __expf(l1 - mx);
        float inv = 1.f / (e0 + e1);
        out[2 * n + 0] = e0 * inv;
        out[2 * n + 1] = e1 * inv;
    }
}

// ---------- host ----------
extern "C" void kernel_launch(void* const* d_in, const int* in_sizes, int n_in,
                              void* d_out, int out_size, void* d_ws, size_t ws_size,
                              hipStream_t stream)
{
    // ws layout — 6,400,000 f32 = 25.6 MB total
    float* var_h = (float*)d_ws;          //   640,000 f32 [NN,64]
    float* nm_v  = var_h + 640000;        //   640,000 f32 [NN,64] atomic accum
    float* fac_h = nm_v + 640000;         // 5,120,000 f32 [NF,64]

    // inputs, consumed directly as f32 / int32 (reference dtypes)
    const int*   f2v_row  = (const int*)d_in[0];
    const int*   f2v_col  = (const int*)d_in[1];
    const int*   v2f_row  = (const int*)d_in[2];
    const float* f2v_feat = (const float*)d_in[4];
    const float* v2f_feat = (const float*)d_in[5];
    const float* W[26];
    for (int j = 0; j < 26; ++j) W[j] = (const float*)d_in[6 + j];
    // W: 0..5 f2v MLP, 6..11 v2f MLP, 12..15 gf GRU, 16..19 gv GRU, 20..25 readout

    k_zero<<<512, 256, 0, stream>>>(var_h, 640000 + 640000 + 5120000);

    for (int s = 0; s < NSTEPS; ++s) {
        // fac -> var messages, scattered into nm_v
        k_edge_scatter<<<NE / 64, 64, 0, stream>>>(
            fac_h, var_h, f2v_row, f2v_col, f2v_feat,
            W[0], W[1], W[2], W[3], W[4], W[5], nm_v);
        // var GRU (consumes nm_v and re-zeros it)
        k_var_gru<<<(NN + 255) / 256, 256, 0, stream>>>(
            nm_v, W[12], W[13], W[14], W[15], var_h);
        // var -> fac: fused messages + pair-reduce + fac GRU
        k_fac_fused<<<NF / 64, 64, 0, stream>>>(
            var_h, fac_h, v2f_row, v2f_feat,
            W[6], W[7], W[8], W[9], W[10], W[11],
            W[16], W[17], W[18], W[19]);
    }
    k_readout<<<(NN + 255) / 256, 256, 0, stream>>>(
        var_h, W[20], W[21], W[22], W[23], W[24], W[25],
        (float*)d_out);
}

// Round 9
// 23717.627 us; speedup vs baseline: 1.2597x; 1.2597x over previous
//
#include <hip/hip_runtime.h>

// Problem constants (fixed by reference setup)
#define NN     10000      // variable nodes
#define NF     80000      // factors
#define NE     160000     // directed edges per direction
#define SDIM   64         // state dim
#define HMDIM  128        // hidden (message MLP)
#define HRDIM  128        // hidden (readout)
#define KIN    136        // 2*S + 8
#define NSTEPS 5

static_assert(NE % 64 == 0, "edge grid exact");

// ---------- helpers ----------
static __device__ __forceinline__ float sigm(float x) {
    x = fminf(fmaxf(x, -30.f), 30.f);
    return 1.f / (1.f + __expf(-x));
}
static __device__ __forceinline__ float tanh_f(float x) {
    x = fminf(fmaxf(x, -15.f), 15.f);
    float t = __expf(2.f * x);
    return (t - 1.f) / (t + 1.f);
}

__global__ void k_zero(float* __restrict__ p, int n) {
    int i = blockIdx.x * blockDim.x + threadIdx.x;
    int stride = gridDim.x * blockDim.x;
    for (; i < n; i += stride) p[i] = 0.f;
}

// ---------- generic edge MLP + atomic scatter ----------
// One lane = one edge. x = [hrow[r] (64), hcol[c] (64), feat[r] (4),
// feat[c] (4)] -> 128 relu -> 128 relu -> 64, atomic-accumulated into
// nm[c]. Weights wave-uniform -> scalar loads. Register budget scheme:
//   h1 low 64 -> regs, h1 high 64 -> LDS (256 B/lane = 16 KB/block),
//   h2 low+high -> regs. Peak ~220 VGPR; __launch_bounds__(64,2) caps 256
//   -> 2 waves/SIMD (8 waves/CU), 3.5x the round-8 occupancy.
__global__ __launch_bounds__(64, 2)
void k_edge_mlp(const float* __restrict__ hrow,    // f32 [*,64] indexed by rows[]
                const float* __restrict__ hcol,    // f32 [*,64] indexed by cols[]
                const int* __restrict__ rows, const int* __restrict__ cols,
                const float* __restrict__ feat,    // f32 [NE,4]
                const float* __restrict__ w1, const float* __restrict__ b1,
                const float* __restrict__ w2, const float* __restrict__ b2,
                const float* __restrict__ w3, const float* __restrict__ b3,
                float* __restrict__ nm)
{
    __shared__ float lbuf[64][64];               // h1 high half [k-64][tid], 16 KB
    const int tid = threadIdx.x;
    const int e = blockIdx.x * 64 + tid;         // grid exact: NE/64 blocks
    const int r = rows[e];
    const int c = cols[e];

    float xr[KIN];
    {
        const float4* pr = (const float4*)(hrow + (size_t)r * SDIM);
        const float4* pc = (const float4*)(hcol + (size_t)c * SDIM);
        #pragma unroll
        for (int i = 0; i < 16; ++i) {
            float4 t = pr[i];
            xr[4*i+0] = t.x; xr[4*i+1] = t.y; xr[4*i+2] = t.z; xr[4*i+3] = t.w;
        }
        #pragma unroll
        for (int i = 0; i < 16; ++i) {
            float4 t = pc[i];
            xr[64+4*i+0] = t.x; xr[64+4*i+1] = t.y; xr[64+4*i+2] = t.z; xr[64+4*i+3] = t.w;
        }
        float4 fr = *(const float4*)(feat + (size_t)r * 4);
        float4 fc = *(const float4*)(feat + (size_t)c * 4);
        xr[128] = fr.x; xr[129] = fr.y; xr[130] = fr.z; xr[131] = fr.w;
        xr[132] = fc.x; xr[133] = fc.y; xr[134] = fc.z; xr[135] = fc.w;
    }

    // ---- layer 1 low: j = 0..63 -> registers ----
    float h1lo[64];
    #pragma unroll
    for (int jc = 0; jc < 64; jc += 8) {
        float acc[8];
        #pragma unroll
        for (int jj = 0; jj < 8; ++jj) acc[jj] = b1[jc + jj];
        #pragma unroll
        for (int k = 0; k < KIN; ++k) {
            float xk = xr[k];
            #pragma unroll
            for (int jj = 0; jj < 8; ++jj)
                acc[jj] = fmaf(w1[(jc + jj) * KIN + k], xk, acc[jj]);
        }
        #pragma unroll
        for (int jj = 0; jj < 8; ++jj) h1lo[jc + jj] = fmaxf(acc[jj], 0.f);
    }
    // ---- layer 1 high: j = 64..127 -> LDS (loop rolled: writes LDS only) ----
    for (int jc = 64; jc < 128; jc += 8) {
        float acc[8];
        #pragma unroll
        for (int jj = 0; jj < 8; ++jj) acc[jj] = b1[jc + jj];
        #pragma unroll
        for (int k = 0; k < KIN; ++k) {
            float xk = xr[k];
            #pragma unroll
            for (int jj = 0; jj < 8; ++jj)
                acc[jj] = fmaf(w1[(jc + jj) * KIN + k], xk, acc[jj]);
        }
        #pragma unroll
        for (int jj = 0; jj < 8; ++jj)
            lbuf[jc - 64 + jj][tid] = fmaxf(acc[jj], 0.f);
    }
    // xr dead from here

    // ---- layer 2 low: j = 0..63 -> registers ----
    float h2lo[64];
    #pragma unroll
    for (int jc = 0; jc < 64; jc += 8) {
        float acc[8];
        #pragma unroll
        for (int jj = 0; jj < 8; ++jj) acc[jj] = b2[jc + jj];
        #pragma unroll
        for (int k = 0; k < 64; ++k) {
            float xk = h1lo[k];
            #pragma unroll
            for (int jj = 0; jj < 8; ++jj)
                acc[jj] = fmaf(w2[(jc + jj) * HMDIM + k], xk, acc[jj]);
        }
        #pragma unroll
        for (int k = 0; k < 64; ++k) {
            float xk = lbuf[k][tid];
            #pragma unroll
            for (int jj = 0; jj < 8; ++jj)
                acc[jj] = fmaf(w2[(jc + jj) * HMDIM + 64 + k], xk, acc[jj]);
        }
        #pragma unroll
        for (int jj = 0; jj < 8; ++jj) h2lo[jc + jj] = fmaxf(acc[jj], 0.f);
    }
    // ---- layer 2 high: j = 64..127 -> registers ----
    float h2hi[64];
    #pragma unroll
    for (int jc = 64; jc < 128; jc += 8) {
        float acc[8];
        #pragma unroll
        for (int jj = 0; jj < 8; ++jj) acc[jj] = b2[jc + jj];
        #pragma unroll
        for (int k = 0; k < 64; ++k) {
            float xk = h1lo[k];
            #pragma unroll
            for (int jj = 0; jj < 8; ++jj)
                acc[jj] = fmaf(w2[(jc + jj) * HMDIM + k], xk, acc[jj]);
        }
        #pragma unroll
        for (int k = 0; k < 64; ++k) {
            float xk = lbuf[k][tid];
            #pragma unroll
            for (int jj = 0; jj < 8; ++jj)
                acc[jj] = fmaf(w2[(jc + jj) * HMDIM + 64 + k], xk, acc[jj]);
        }
        #pragma unroll
        for (int jj = 0; jj < 8; ++jj) h2hi[jc - 64 + jj] = fmaxf(acc[jj], 0.f);
    }
    // h1 dead from here

    // ---- layer 3: 64 outputs, atomic accumulate into nm[c] (loop rolled) ----
    float* no = nm + (size_t)c * 64;
    for (int jc = 0; jc < 64; jc += 8) {
        float acc[8];
        #pragma unroll
        for (int jj = 0; jj < 8; ++jj) acc[jj] = b3[jc + jj];
        #pragma unroll
        for (int k = 0; k < 64; ++k) {
            float xk = h2lo[k];
            #pragma unroll
            for (int jj = 0; jj < 8; ++jj)
                acc[jj] = fmaf(w3[(jc + jj) * HMDIM + k], xk, acc[jj]);
        }
        #pragma unroll
        for (int k = 0; k < 64; ++k) {
            float xk = h2hi[k];
            #pragma unroll
            for (int jj = 0; jj < 8; ++jj)
                acc[jj] = fmaf(w3[(jc + jj) * HMDIM + 64 + k], xk, acc[jj]);
        }
        #pragma unroll
        for (int jj = 0; jj < 8; ++jj) atomicAdd(&no[jc + jj], acc[jj]);
    }
}

// ---------- generic GRU: h = GRU(nm, h); zeroes consumed nm rows ----------
__global__ __launch_bounds__(256)
void k_gru(float* __restrict__ nm,
           const float* __restrict__ wih, const float* __restrict__ whh,
           const float* __restrict__ bih, const float* __restrict__ bhh,
           float* __restrict__ hst, int count)
{
    int n0 = blockIdx.x * 256 + threadIdx.x;
    int n = n0 < count ? n0 : count - 1;           // clamp keeps CF uniform
    float m[SDIM], h[SDIM];
    {
        const float4* m4 = (const float4*)(nm + (size_t)n * 64);
        const float4* h4 = (const float4*)(hst + (size_t)n * 64);
        #pragma unroll
        for (int q = 0; q < 16; ++q) {
            float4 t = m4[q];
            m[4*q+0] = t.x; m[4*q+1] = t.y; m[4*q+2] = t.z; m[4*q+3] = t.w;
        }
        #pragma unroll
        for (int q = 0; q < 16; ++q) {
            float4 t = h4[q];
            h[4*q+0] = t.x; h[4*q+1] = t.y; h[4*q+2] = t.z; h[4*q+3] = t.w;
        }
    }
    float hn[SDIM];
    for (int jc = 0; jc < SDIM; jc += 4) {
        float air[4], aiz[4], ain[4], ahr[4], ahz[4], ahn[4];
        #pragma unroll
        for (int jj = 0; jj < 4; ++jj) {
            int j = jc + jj;
            air[jj] = bih[j];       aiz[jj] = bih[64 + j];  ain[jj] = bih[128 + j];
            ahr[jj] = bhh[j];       ahz[jj] = bhh[64 + j];  ahn[jj] = bhh[128 + j];
        }
        #pragma unroll
        for (int k = 0; k < SDIM; ++k) {
            float xk = m[k], hk = h[k];
            #pragma unroll
            for (int jj = 0; jj < 4; ++jj) {
                int j = jc + jj;
                air[jj] = fmaf(wih[j * 64 + k],         xk, air[jj]);
                aiz[jj] = fmaf(wih[(64 + j) * 64 + k],  xk, aiz[jj]);
                ain[jj] = fmaf(wih[(128 + j) * 64 + k], xk, ain[jj]);
                ahr[jj] = fmaf(whh[j * 64 + k],         hk, ahr[jj]);
                ahz[jj] = fmaf(whh[(64 + j) * 64 + k],  hk, ahz[jj]);
                ahn[jj] = fmaf(whh[(128 + j) * 64 + k], hk, ahn[jj]);
            }
        }
        #pragma unroll
        for (int jj = 0; jj < 4; ++jj) {
            float r = sigm(air[jj] + ahr[jj]);
            float z = sigm(aiz[jj] + ahz[jj]);
            float t = tanh_f(ain[jj] + r * ahn[jj]);
            hn[jc + jj] = (1.f - z) * t + z * h[jc + jj];
        }
    }
    if (n0 < count) {
        float4* ho = (float4*)(hst + (size_t)n * 64);
        float4* mo = (float4*)(nm + (size_t)n * 64);
        #pragma unroll
        for (int q = 0; q < 16; ++q) {
            ho[q] = make_float4(hn[4*q+0], hn[4*q+1], hn[4*q+2], hn[4*q+3]);
            mo[q] = make_float4(0.f, 0.f, 0.f, 0.f);   // ready for next scatter
        }
    }
}

// ---------- readout MLP + 2-class softmax -> f32 output ----------
__global__ __launch_bounds__(256)
void k_readout(const float* __restrict__ vh,
               const float* __restrict__ w1, const float* __restrict__ b1,
               const float* __restrict__ w2, const float* __restrict__ b2,
               const float* __restrict__ w3, const float* __restrict__ b3,
               float* __restrict__ out)
{
    int n0 = blockIdx.x * 256 + threadIdx.x;
    int n = n0 < NN ? n0 : NN - 1;
    float x[SDIM];
    {
        const float4* h4 = (const float4*)(vh + (size_t)n * 64);
        #pragma unroll
        for (int q = 0; q < 16; ++q) {
            float4 t = h4[q];
            x[4*q+0] = t.x; x[4*q+1] = t.y; x[4*q+2] = t.z; x[4*q+3] = t.w;
        }
    }
    float h1[HRDIM];
    for (int jc = 0; jc < HRDIM; jc += 8) {
        float acc[8];
        #pragma unroll
        for (int jj = 0; jj < 8; ++jj) acc[jj] = b1[jc + jj];
        #pragma unroll
        for (int k = 0; k < SDIM; ++k) {
            float xk = x[k];
            #pragma unroll
            for (int jj = 0; jj < 8; ++jj)
                acc[jj] = fmaf(w1[(jc + jj) * SDIM + k], xk, acc[jj]);
        }
        #pragma unroll
        for (int jj = 0; jj < 8; ++jj) h1[jc + jj] = fmaxf(acc[jj], 0.f);
    }
    float l0 = b3[0], l1 = b3[1];
    for (int jc = 0; jc < HRDIM; jc += 8) {
        float acc[8];
        #pragma unroll
        for (int jj = 0; jj < 8; ++jj) acc[jj] = b2[jc + jj];
        #pragma unroll
        for (int k = 0; k < HRDIM; ++k) {
            float xk = h1[k];
            #pragma unroll
            for (int jj = 0; jj < 8; ++jj)
                acc[jj] = fmaf(w2[(jc + jj) * HRDIM + k], xk, acc[jj]);
        }
        #pragma unroll
        for (int jj = 0; jj < 8; ++jj) {
            float v = fmaxf(acc[jj], 0.f);
            l0 = fmaf(w3[jc + jj], v, l0);
            l1 = fmaf(w3[HRDIM + jc + jj], v, l1);
        }
    }
    if (n0 < NN) {
        float mx = fmaxf(l0, l1);
        float e0 = __expf(l0 - mx), e1 = __expf(l1 - mx);
        float inv = 1.f / (e0 + e1);
        out[2 * n + 0] = e0 * inv;
        out[2 * n + 1] = e1 * inv;
    }
}

// ---------- host ----------
extern "C" void kernel_launch(void* const* d_in, const int* in_sizes, int n_in,
                              void* d_out, int out_size, void* d_ws, size_t ws_size,
                              hipStream_t stream)
{
    // ws layout — 10,880,000 f32 = 43.52 MB (R1 empirically ran at 44.9 MB)
    float* var_h = (float*)d_ws;          //   640,000 f32 [NN,64]
    float* fac_h = var_h + 640000;        // 5,120,000 f32 [NF,64]
    float* nm    = fac_h + 5120000;       // 5,120,000 f32 [NF,64] shared accum
                                          //   (var phase uses rows 0..NN-1)

    const int*   f2v_row  = (const int*)d_in[0];
    const int*   f2v_col  = (const int*)d_in[1];
    const int*   v2f_row  = (const int*)d_in[2];
    const int*   v2f_col  = (const int*)d_in[3];
    const float* f2v_feat = (const float*)d_in[4];
    const float* v2f_feat = (const float*)d_in[5];
    const float* W[26];
    for (int j = 0; j < 26; ++j) W[j] = (const float*)d_in[6 + j];
    // W: 0..5 f2v MLP, 6..11 v2f MLP, 12..15 gf GRU, 16..19 gv GRU, 20..25 readout

    k_zero<<<512, 256, 0, stream>>>(var_h, 640000 + 5120000 + 5120000);

    for (int s = 0; s < NSTEPS; ++s) {
        // fac -> var messages into nm[node]; var GRU
        k_edge_mlp<<<NE / 64, 64, 0, stream>>>(
            fac_h, var_h, f2v_row, f2v_col, f2v_feat,
            W[0], W[1], W[2], W[3], W[4], W[5], nm);
        k_gru<<<(NN + 255) / 256, 256, 0, stream>>>(
            nm, W[12], W[13], W[14], W[15], var_h, NN);
        // var -> fac messages into nm[factor]; fac GRU
        k_edge_mlp<<<NE / 64, 64, 0, stream>>>(
            var_h, fac_h, v2f_row, v2f_col, v2f_feat,
            W[6], W[7], W[8], W[9], W[10], W[11], nm);
        k_gru<<<(NF + 255) / 256, 256, 0, stream>>>(
            nm, W[16], W[17], W[18], W[19], fac_h, NF);
    }
    k_readout<<<(NN + 255) / 256, 256, 0, stream>>>(
        var_h, W[20], W[21], W[22], W[23], W[24], W[25],
        (float*)d_out);
}

// Round 10
// 18800.307 us; speedup vs baseline: 1.5891x; 1.2616x over previous
//
#include <hip/hip_runtime.h>

// Problem constants (fixed by reference setup)
#define NN     10000      // variable nodes
#define NF     80000      // factors
#define NE     160000     // directed edges per direction
#define SDIM   64         // state dim
#define HMDIM  128        // hidden (message MLP)
#define HRDIM  128        // hidden (readout)
#define KIN    136        // 2*S + 8
#define NSTEPS 5

static_assert(NE % 64 == 0, "edge grid exact");
static_assert(NF % 64 == 0, "factor grid exact");

// ---------- helpers ----------
static __device__ __forceinline__ float sigm(float x) {
    x = fminf(fmaxf(x, -30.f), 30.f);
    return 1.f / (1.f + __expf(-x));
}
static __device__ __forceinline__ float tanh_f(float x) {
    x = fminf(fmaxf(x, -15.f), 15.f);
    float t = __expf(2.f * x);
    return (t - 1.f) / (t + 1.f);
}

__global__ void k_zero(float* __restrict__ p, int n) {
    int i = blockIdx.x * blockDim.x + threadIdx.x;
    int stride = gridDim.x * blockDim.x;
    for (; i < n; i += stride) p[i] = 0.f;
}

// ---------- tiled edge MLP + atomic scatter ----------
// Block = 256 threads = 4 waves over the SAME 64 edges (lane = edge).
// Wave w computes j-chunk [32w,32w+32) of each hidden layer (wave-uniform j
// -> weights via scalar loads), activations cross layers via LDS H[j][lane].
// Max one big register array live at a time (xr[136] then hreg[128]) -> no
// scratch spill (round-9 failure mode: 3 arrays live -> 360 MB spill traffic).
__global__ __launch_bounds__(256, 2)
void k_edge_mlp(const float* __restrict__ hrow,    // f32 [*,64] indexed by rows[]
                const float* __restrict__ hcol,    // f32 [*,64] indexed by cols[]
                const int* __restrict__ rows, const int* __restrict__ cols,
                const float* __restrict__ feat,    // f32 [NE,4]
                const float* __restrict__ w1, const float* __restrict__ b1,
                const float* __restrict__ w2, const float* __restrict__ b2,
                const float* __restrict__ w3, const float* __restrict__ b3,
                float* __restrict__ nm)
{
    __shared__ float H[HMDIM][64];               // 32 KB; [j][lane] conflict-free
    const int tid  = threadIdx.x;
    const int lane = tid & 63;
    const int wv   = tid >> 6;                   // 0..3
    const int e = blockIdx.x * 64 + lane;        // grid exact: NE/64 blocks
    const int r = rows[e];
    const int c = cols[e];

    float xr[KIN];
    {
        const float4* pr = (const float4*)(hrow + (size_t)r * SDIM);
        const float4* pc = (const float4*)(hcol + (size_t)c * SDIM);
        #pragma unroll
        for (int i = 0; i < 16; ++i) {
            float4 t = pr[i];
            xr[4*i+0] = t.x; xr[4*i+1] = t.y; xr[4*i+2] = t.z; xr[4*i+3] = t.w;
        }
        #pragma unroll
        for (int i = 0; i < 16; ++i) {
            float4 t = pc[i];
            xr[64+4*i+0] = t.x; xr[64+4*i+1] = t.y; xr[64+4*i+2] = t.z; xr[64+4*i+3] = t.w;
        }
        float4 fr = *(const float4*)(feat + (size_t)r * 4);
        float4 fc = *(const float4*)(feat + (size_t)c * 4);
        xr[128] = fr.x; xr[129] = fr.y; xr[130] = fr.z; xr[131] = fr.w;
        xr[132] = fc.x; xr[133] = fc.y; xr[134] = fc.z; xr[135] = fc.w;
    }

    // ---- layer 1: wave computes j in [32wv, 32wv+32) ----
    {
        const int j0 = 32 * wv;
        for (int jc = 0; jc < 32; jc += 8) {
            float acc[8];
            #pragma unroll
            for (int jj = 0; jj < 8; ++jj) acc[jj] = b1[j0 + jc + jj];
            #pragma unroll
            for (int k = 0; k < KIN; ++k) {
                float xk = xr[k];
                #pragma unroll
                for (int jj = 0; jj < 8; ++jj)
                    acc[jj] = fmaf(w1[(j0 + jc + jj) * KIN + k], xk, acc[jj]);
            }
            #pragma unroll
            for (int jj = 0; jj < 8; ++jj)
                H[j0 + jc + jj][lane] = fmaxf(acc[jj], 0.f);
        }
    }
    __syncthreads();
    // xr dead; pull full h1 into registers
    float hreg[HMDIM];
    #pragma unroll
    for (int k = 0; k < HMDIM; ++k) hreg[k] = H[k][lane];
    __syncthreads();                              // everyone read before overwrite

    // ---- layer 2: wave computes j in [32wv, 32wv+32) ----
    {
        const int j0 = 32 * wv;
        for (int jc = 0; jc < 32; jc += 8) {
            float acc[8];
            #pragma unroll
            for (int jj = 0; jj < 8; ++jj) acc[jj] = b2[j0 + jc + jj];
            #pragma unroll
            for (int k = 0; k < HMDIM; ++k) {
                float xk = hreg[k];
                #pragma unroll
                for (int jj = 0; jj < 8; ++jj)
                    acc[jj] = fmaf(w2[(j0 + jc + jj) * HMDIM + k], xk, acc[jj]);
            }
            #pragma unroll
            for (int jj = 0; jj < 8; ++jj)
                H[j0 + jc + jj][lane] = fmaxf(acc[jj], 0.f);
        }
    }
    __syncthreads();
    #pragma unroll
    for (int k = 0; k < HMDIM; ++k) hreg[k] = H[k][lane];   // h2

    // ---- layer 3: wave computes j in [16wv, 16wv+16), atomic into nm[c] ----
    {
        const int j0 = 16 * wv;
        float* no = nm + (size_t)c * 64;
        for (int jc = 0; jc < 16; jc += 8) {
            float acc[8];
            #pragma unroll
            for (int jj = 0; jj < 8; ++jj) acc[jj] = b3[j0 + jc + jj];
            #pragma unroll
            for (int k = 0; k < HMDIM; ++k) {
                float xk = hreg[k];
                #pragma unroll
                for (int jj = 0; jj < 8; ++jj)
                    acc[jj] = fmaf(w3[(j0 + jc + jj) * HMDIM + k], xk, acc[jj]);
            }
            #pragma unroll
            for (int jj = 0; jj < 8; ++jj) atomicAdd(&no[j0 + jc + jj], acc[jj]);
        }
    }
}

// ---------- GRU: block = 4 waves over 64 rows; wave w computes 16 outputs ----------
// h = GRU(nm, h); zeroes consumed nm rows for the next scatter.
__global__ __launch_bounds__(256, 2)
void k_gru(float* __restrict__ nm,
           const float* __restrict__ wih, const float* __restrict__ whh,
           const float* __restrict__ bih, const float* __restrict__ bhh,
           float* __restrict__ hst, int count)
{
    const int lane = threadIdx.x & 63;
    const int wv   = threadIdx.x >> 6;
    const int row0 = blockIdx.x * 64 + lane;
    const int row  = row0 < count ? row0 : count - 1;
    const int j0   = 16 * wv;

    float m[SDIM], h[SDIM];
    {
        const float4* m4 = (const float4*)(nm + (size_t)row * 64);
        const float4* h4 = (const float4*)(hst + (size_t)row * 64);
        #pragma unroll
        for (int q = 0; q < 16; ++q) {
            float4 t = m4[q];
            m[4*q+0] = t.x; m[4*q+1] = t.y; m[4*q+2] = t.z; m[4*q+3] = t.w;
        }
        #pragma unroll
        for (int q = 0; q < 16; ++q) {
            float4 t = h4[q];
            h[4*q+0] = t.x; h[4*q+1] = t.y; h[4*q+2] = t.z; h[4*q+3] = t.w;
        }
    }
    __syncthreads();   // all waves loaded m,h before anyone stores/zeroes

    for (int jc = 0; jc < 16; jc += 4) {
        float air[4], aiz[4], ain[4], ahr[4], ahz[4], ahn[4];
        #pragma unroll
        for (int jj = 0; jj < 4; ++jj) {
            int j = j0 + jc + jj;
            air[jj] = bih[j];       aiz[jj] = bih[64 + j];  ain[jj] = bih[128 + j];
            ahr[jj] = bhh[j];       ahz[jj] = bhh[64 + j];  ahn[jj] = bhh[128 + j];
        }
        #pragma unroll
        for (int k = 0; k < SDIM; ++k) {
            float xk = m[k], hk = h[k];
            #pragma unroll
            for (int jj = 0; jj < 4; ++jj) {
                int j = j0 + jc + jj;
                air[jj] = fmaf(wih[j * 64 + k],         xk, air[jj]);
                aiz[jj] = fmaf(wih[(64 + j) * 64 + k],  xk, aiz[jj]);
                ain[jj] = fmaf(wih[(128 + j) * 64 + k], xk, ain[jj]);
                ahr[jj] = fmaf(whh[j * 64 + k],         hk, ahr[jj]);
                ahz[jj] = fmaf(whh[(64 + j) * 64 + k],  hk, ahz[jj]);
                ahn[jj] = fmaf(whh[(128 + j) * 64 + k], hk, ahn[jj]);
            }
        }
        if (row0 < count) {
            float hn[4];
            #pragma unroll
            for (int jj = 0; jj < 4; ++jj) {
                float r = sigm(air[jj] + ahr[jj]);
                float z = sigm(aiz[jj] + ahz[jj]);
                float t = tanh_f(ain[jj] + r * ahn[jj]);
                hn[jj] = (1.f - z) * t + z * h[j0 + jc + jj];
            }
            *(float4*)(hst + (size_t)row * 64 + j0 + jc) =
                make_float4(hn[0], hn[1], hn[2], hn[3]);
        }
    }
    if (row0 < count) {
        float4* mo = (float4*)(nm + (size_t)row * 64 + j0);
        #pragma unroll
        for (int q = 0; q < 4; ++q) mo[q] = make_float4(0.f, 0.f, 0.f, 0.f);
    }
}

// ---------- readout: tiled like edge MLP; softmax -> f32 output ----------
__global__ __launch_bounds__(256, 2)
void k_readout(const float* __restrict__ vh,
               const float* __restrict__ w1, const float* __restrict__ b1,
               const float* __restrict__ w2, const float* __restrict__ b2,
               const float* __restrict__ w3, const float* __restrict__ b3,
               float* __restrict__ out)
{
    __shared__ float H[HRDIM][64];               // 32 KB
    const int tid  = threadIdx.x;
    const int lane = tid & 63;
    const int wv   = tid >> 6;
    const int n0 = blockIdx.x * 64 + lane;
    const int n  = n0 < NN ? n0 : NN - 1;

    float x[SDIM];
    {
        const float4* h4 = (const float4*)(vh + (size_t)n * 64);
        #pragma unroll
        for (int q = 0; q < 16; ++q) {
            float4 t = h4[q];
            x[4*q+0] = t.x; x[4*q+1] = t.y; x[4*q+2] = t.z; x[4*q+3] = t.w;
        }
    }
    // layer 1: wave computes j in [32wv, 32wv+32)
    {
        const int j0 = 32 * wv;
        for (int jc = 0; jc < 32; jc += 8) {
            float acc[8];
            #pragma unroll
            for (int jj = 0; jj < 8; ++jj) acc[jj] = b1[j0 + jc + jj];
            #pragma unroll
            for (int k = 0; k < SDIM; ++k) {
                float xk = x[k];
                #pragma unroll
                for (int jj = 0; jj < 8; ++jj)
                    acc[jj] = fmaf(w1[(j0 + jc + jj) * SDIM + k], xk, acc[jj]);
            }
            #pragma unroll
            for (int jj = 0; jj < 8; ++jj)
                H[j0 + jc + jj][lane] = fmaxf(acc[jj], 0.f);
        }
    }
    __syncthreads();
    float hreg[HRDIM];
    #pragma unroll
    for (int k = 0; k < HRDIM; ++k) hreg[k] = H[k][lane];
    __syncthreads();
    // layer 2
    {
        const int j0 = 32 * wv;
        for (int jc = 0; jc < 32; jc += 8) {
            float acc[8];
            #pragma unroll
            for (int jj = 0; jj < 8; ++jj) acc[jj] = b2[j0 + jc + jj];
            #pragma unroll
            for (int k = 0; k < HRDIM; ++k) {
                float xk = hreg[k];
                #pragma unroll
                for (int jj = 0; jj < 8; ++jj)
                    acc[jj] = fmaf(w2[(j0 + jc + jj) * HRDIM + k], xk, acc[jj]);
            }
            #pragma unroll
            for (int jj = 0; jj < 8; ++jj)
                H[j0 + jc + jj][lane] = fmaxf(acc[jj], 0.f);
        }
    }
    __syncthreads();
    if (wv == 0 && n0 < NN) {
        #pragma unroll
        for (int k = 0; k < HRDIM; ++k) hreg[k] = H[k][lane];   // h2 (relu'd)
        float l0 = b3[0], l1 = b3[1];
        #pragma unroll
        for (int k = 0; k < HRDIM; ++k) {
            l0 = fmaf(w3[k],         hreg[k], l0);
            l1 = fmaf(w3[HRDIM + k], hreg[k], l1);
        }
        float mx = fmaxf(l0, l1);
        float e0 = __expf(l0 - mx), e1 = __expf(l1 - mx);
        float inv = 1.f / (e0 + e1);
        out[2 * n + 0] = e0 * inv;
        out[2 * n + 1] = e1 * inv;
    }
}

// ---------- host ----------
extern "C" void kernel_launch(void* const* d_in, const int* in_sizes, int n_in,
                              void* d_out, int out_size, void* d_ws, size_t ws_size,
                              hipStream_t stream)
{
    // ws layout — 10,880,000 f32 = 43.52 MB (R1 empirically ran at 44.9 MB)
    float* var_h = (float*)d_ws;          //   640,000 f32 [NN,64]
    float* fac_h = var_h + 640000;        // 5,120,000 f32 [NF,64]
    float* nm    = fac_h + 5120000;       // 5,120,000 f32 [NF,64] shared accum
                                          //   (var phase uses rows 0..NN-1)

    const int*   f2v_row  = (const int*)d_in[0];
    const int*   f2v_col  = (const int*)d_in[1];
    const int*   v2f_row  = (const int*)d_in[2];
    const int*   v2f_col  = (const int*)d_in[3];
    const float* f2v_feat = (const float*)d_in[4];
    const float* v2f_feat = (const float*)d_in[5];
    const float* W[26];
    for (int j = 0; j < 26; ++j) W[j] = (const float*)d_in[6 + j];
    // W: 0..5 f2v MLP, 6..11 v2f MLP, 12..15 gf GRU, 16..19 gv GRU, 20..25 readout

    k_zero<<<512, 256, 0, stream>>>(var_h, 640000 + 5120000 + 5120000);

    for (int s = 0; s < NSTEPS; ++s) {
        // fac -> var messages into nm[node]; var GRU
        k_edge_mlp<<<NE / 64, 256, 0, stream>>>(
            fac_h, var_h, f2v_row, f2v_col, f2v_feat,
            W[0], W[1], W[2], W[3], W[4], W[5], nm);
        k_gru<<<(NN + 63) / 64, 256, 0, stream>>>(
            nm, W[12], W[13], W[14], W[15], var_h, NN);
        // var -> fac messages into nm[factor]; fac GRU
        k_edge_mlp<<<NE / 64, 256, 0, stream>>>(
            var_h, fac_h, v2f_row, v2f_col, v2f_feat,
            W[6], W[7], W[8], W[9], W[10], W[11], nm);
        k_gru<<<(NF + 63) / 64, 256, 0, stream>>>(
            nm, W[16], W[17], W[18], W[19], fac_h, NF);
    }
    k_readout<<<(NN + 63) / 64, 256, 0, stream>>>(
        var_h, W[20], W[21], W[22], W[23], W[24], W[25],
        (float*)d_out);
}

// Round 11
// 8219.495 us; speedup vs baseline: 3.6348x; 2.2873x over previous
//
#include <hip/hip_runtime.h>

// Problem constants (fixed by reference setup)
#define NN     10000      // variable nodes
#define NF     80000      // factors
#define NE     160000     // directed edges per direction
#define SDIM   64         // state dim
#define HMDIM  128        // hidden (message MLP)
#define HRDIM  128        // hidden (readout)
#define KIN    136        // 2*S + 8
#define NSTEPS 5

static_assert(NE % 64 == 0, "edge grid exact");

// ---------- helpers ----------
static __device__ __forceinline__ float sigm(float x) {
    x = fminf(fmaxf(x, -30.f), 30.f);
    return 1.f / (1.f + __expf(-x));
}
static __device__ __forceinline__ float tanh_f(float x) {
    x = fminf(fmaxf(x, -15.f), 15.f);
    float t = __expf(2.f * x);
    return (t - 1.f) / (t + 1.f);
}

__global__ void k_zero(float* __restrict__ p, int n) {
    int i = blockIdx.x * blockDim.x + threadIdx.x;
    int stride = gridDim.x * blockDim.x;
    for (; i < n; i += stride) p[i] = 0.f;
}

// ---------- tiled edge MLP + atomic scatter (no big per-lane arrays) ----------
// Block = 256 threads = 4 waves over the SAME 64 edges (lane = edge).
// Wave w owns j-chunk [32w,32w+32) (wave-uniform -> scalar weight loads).
// Layer-1 input is STREAMED from global float4-at-a-time (never held as an
// array); hidden activations live only in LDS H[j][lane] and are STREAMED
// back in the k-loops. Per-lane register state <= acc[32] -> no scratch
// (rounds 9/10 failure: >64-float arrays always spill on gfx950).
__global__ __launch_bounds__(256, 3)
void k_edge_mlp(const float* __restrict__ hrow,    // f32 [*,64] indexed by rows[]
                const float* __restrict__ hcol,    // f32 [*,64] indexed by cols[]
                const int* __restrict__ rows, const int* __restrict__ cols,
                const float* __restrict__ feat,    // f32 [NE,4]
                const float* __restrict__ w1, const float* __restrict__ b1,
                const float* __restrict__ w2, const float* __restrict__ b2,
                const float* __restrict__ w3, const float* __restrict__ b3,
                float* __restrict__ nm)
{
    __shared__ float H[HMDIM][64];               // 32 KB; [j][lane] 2-way free
    const int lane = threadIdx.x & 63;
    const int wv   = __builtin_amdgcn_readfirstlane(threadIdx.x >> 6);  // 0..3
    const int e = blockIdx.x * 64 + lane;        // grid exact: NE/64 blocks
    const int r = rows[e];
    const int c = cols[e];
    const float4* pr = (const float4*)(hrow + (size_t)r * SDIM);
    const float4* pc = (const float4*)(hcol + (size_t)c * SDIM);

    const int j1 = 32 * wv;                      // layer-1/2 chunk base
    float acc[32];
    #pragma unroll
    for (int j = 0; j < 32; ++j) acc[j] = b1[j1 + j];

    // ---- layer 1: stream input from global; k = 0..63 (hrow) ----
    #pragma unroll 4
    for (int q = 0; q < 16; ++q) {
        float4 x4 = pr[q];
        #pragma unroll
        for (int j = 0; j < 32; ++j) {
            const float* wr = w1 + (j1 + j) * KIN + 4 * q;
            acc[j] = fmaf(wr[0], x4.x, acc[j]);
            acc[j] = fmaf(wr[1], x4.y, acc[j]);
            acc[j] = fmaf(wr[2], x4.z, acc[j]);
            acc[j] = fmaf(wr[3], x4.w, acc[j]);
        }
    }
    // k = 64..127 (hcol)
    #pragma unroll 4
    for (int q = 0; q < 16; ++q) {
        float4 x4 = pc[q];
        #pragma unroll
        for (int j = 0; j < 32; ++j) {
            const float* wr = w1 + (j1 + j) * KIN + 64 + 4 * q;
            acc[j] = fmaf(wr[0], x4.x, acc[j]);
            acc[j] = fmaf(wr[1], x4.y, acc[j]);
            acc[j] = fmaf(wr[2], x4.z, acc[j]);
            acc[j] = fmaf(wr[3], x4.w, acc[j]);
        }
    }
    // k = 128..135 (feat[r], feat[c])
    {
        float4 fr = *(const float4*)(feat + (size_t)r * 4);
        float4 fc = *(const float4*)(feat + (size_t)c * 4);
        #pragma unroll
        for (int j = 0; j < 32; ++j) {
            const float* wr = w1 + (j1 + j) * KIN + 128;
            acc[j] = fmaf(wr[0], fr.x, acc[j]);
            acc[j] = fmaf(wr[1], fr.y, acc[j]);
            acc[j] = fmaf(wr[2], fr.z, acc[j]);
            acc[j] = fmaf(wr[3], fr.w, acc[j]);
            acc[j] = fmaf(wr[4], fc.x, acc[j]);
            acc[j] = fmaf(wr[5], fc.y, acc[j]);
            acc[j] = fmaf(wr[6], fc.z, acc[j]);
            acc[j] = fmaf(wr[7], fc.w, acc[j]);
        }
    }
    #pragma unroll
    for (int j = 0; j < 32; ++j) H[j1 + j][lane] = fmaxf(acc[j], 0.f);
    __syncthreads();

    // ---- layer 2: stream h1 from LDS; compute-all, then sync, then write ----
    #pragma unroll
    for (int j = 0; j < 32; ++j) acc[j] = b2[j1 + j];
    #pragma unroll 8
    for (int k = 0; k < HMDIM; ++k) {
        float xk = H[k][lane];
        #pragma unroll
        for (int j = 0; j < 32; ++j)
            acc[j] = fmaf(w2[(j1 + j) * HMDIM + k], xk, acc[j]);
    }
    __syncthreads();                             // all reads of h1 done
    #pragma unroll
    for (int j = 0; j < 32; ++j) H[j1 + j][lane] = fmaxf(acc[j], 0.f);
    __syncthreads();

    // ---- layer 3: wave computes j in [16wv,16wv+16); atomic into nm[c] ----
    {
        const int j3 = 16 * wv;
        float a3[16];
        #pragma unroll
        for (int j = 0; j < 16; ++j) a3[j] = b3[j3 + j];
        #pragma unroll 8
        for (int k = 0; k < HMDIM; ++k) {
            float xk = H[k][lane];
            #pragma unroll
            for (int j = 0; j < 16; ++j)
                a3[j] = fmaf(w3[(j3 + j) * HMDIM + k], xk, a3[j]);
        }
        float* no = nm + (size_t)c * 64 + j3;
        #pragma unroll
        for (int j = 0; j < 16; ++j) atomicAdd(&no[j], a3[j]);
    }
}

// ---------- GRU: 64 rows/block, 4 waves; m,h staged in LDS, streamed ----------
__global__ __launch_bounds__(256, 3)
void k_gru(float* __restrict__ nm,
           const float* __restrict__ wih, const float* __restrict__ whh,
           const float* __restrict__ bih, const float* __restrict__ bhh,
           float* __restrict__ hst, int count)
{
    __shared__ float M[SDIM][64];                // 16 KB
    __shared__ float Hs[SDIM][64];               // 16 KB
    const int lane = threadIdx.x & 63;
    const int wv   = __builtin_amdgcn_readfirstlane(threadIdx.x >> 6);
    const int row0 = blockIdx.x * 64 + lane;
    const int row  = row0 < count ? row0 : count - 1;
    const float4* m4 = (const float4*)(nm + (size_t)row * 64);
    const float4* h4 = (const float4*)(hst + (size_t)row * 64);

    // stage: wave w loads float4 chunks [4w,4w+4) of its lane's row
    #pragma unroll
    for (int qq = 0; qq < 4; ++qq) {
        int q = 4 * wv + qq;
        float4 tm = m4[q], th = h4[q];
        M[4*q+0][lane] = tm.x; M[4*q+1][lane] = tm.y;
        M[4*q+2][lane] = tm.z; M[4*q+3][lane] = tm.w;
        Hs[4*q+0][lane] = th.x; Hs[4*q+1][lane] = th.y;
        Hs[4*q+2][lane] = th.z; Hs[4*q+3][lane] = th.w;
    }
    __syncthreads();

    const int j0 = 16 * wv;                      // this wave's 16 outputs
    for (int jc = 0; jc < 16; jc += 4) {
        float air[4], aiz[4], ain[4], ahr[4], ahz[4], ahn[4];
        #pragma unroll
        for (int jj = 0; jj < 4; ++jj) {
            int j = j0 + jc + jj;
            air[jj] = bih[j];       aiz[jj] = bih[64 + j];  ain[jj] = bih[128 + j];
            ahr[jj] = bhh[j];       ahz[jj] = bhh[64 + j];  ahn[jj] = bhh[128 + j];
        }
        #pragma unroll 8
        for (int k = 0; k < SDIM; ++k) {
            float xk = M[k][lane], hk = Hs[k][lane];
            #pragma unroll
            for (int jj = 0; jj < 4; ++jj) {
                int j = j0 + jc + jj;
                air[jj] = fmaf(wih[j * 64 + k],         xk, air[jj]);
                aiz[jj] = fmaf(wih[(64 + j) * 64 + k],  xk, aiz[jj]);
                ain[jj] = fmaf(wih[(128 + j) * 64 + k], xk, ain[jj]);
                ahr[jj] = fmaf(whh[j * 64 + k],         hk, ahr[jj]);
                ahz[jj] = fmaf(whh[(64 + j) * 64 + k],  hk, ahz[jj]);
                ahn[jj] = fmaf(whh[(128 + j) * 64 + k], hk, ahn[jj]);
            }
        }
        if (row0 < count) {
            float hn[4];
            #pragma unroll
            for (int jj = 0; jj < 4; ++jj) {
                int j = j0 + jc + jj;
                float r = sigm(air[jj] + ahr[jj]);
                float z = sigm(aiz[jj] + ahz[jj]);
                float t = tanh_f(ain[jj] + r * ahn[jj]);
                hn[jj] = (1.f - z) * t + z * Hs[j][lane];
            }
            *(float4*)(hst + (size_t)row * 64 + j0 + jc) =
                make_float4(hn[0], hn[1], hn[2], hn[3]);
        }
    }
    // zero consumed nm chunks (this wave's staged quarter)
    if (row0 < count) {
        float4* mo = (float4*)(nm + (size_t)row * 64);
        #pragma unroll
        for (int qq = 0; qq < 4; ++qq)
            mo[4 * wv + qq] = make_float4(0.f, 0.f, 0.f, 0.f);
    }
}

// ---------- readout: tiled; softmax -> f32 output ----------
__global__ __launch_bounds__(256, 3)
void k_readout(const float* __restrict__ vh,
               const float* __restrict__ w1, const float* __restrict__ b1,
               const float* __restrict__ w2, const float* __restrict__ b2,
               const float* __restrict__ w3, const float* __restrict__ b3,
               float* __restrict__ out)
{
    __shared__ float H[HRDIM][64];               // 32 KB
    const int lane = threadIdx.x & 63;
    const int wv   = __builtin_amdgcn_readfirstlane(threadIdx.x >> 6);
    const int n0 = blockIdx.x * 64 + lane;
    const int n  = n0 < NN ? n0 : NN - 1;
    const float4* px = (const float4*)(vh + (size_t)n * 64);

    const int j1 = 32 * wv;
    float acc[32];
    #pragma unroll
    for (int j = 0; j < 32; ++j) acc[j] = b1[j1 + j];
    #pragma unroll 4
    for (int q = 0; q < 16; ++q) {
        float4 x4 = px[q];
        #pragma unroll
        for (int j = 0; j < 32; ++j) {
            const float* wr = w1 + (j1 + j) * SDIM + 4 * q;
            acc[j] = fmaf(wr[0], x4.x, acc[j]);
            acc[j] = fmaf(wr[1], x4.y, acc[j]);
            acc[j] = fmaf(wr[2], x4.z, acc[j]);
            acc[j] = fmaf(wr[3], x4.w, acc[j]);
        }
    }
    #pragma unroll
    for (int j = 0; j < 32; ++j) H[j1 + j][lane] = fmaxf(acc[j], 0.f);
    __syncthreads();

    #pragma unroll
    for (int j = 0; j < 32; ++j) acc[j] = b2[j1 + j];
    #pragma unroll 8
    for (int k = 0; k < HRDIM; ++k) {
        float xk = H[k][lane];
        #pragma unroll
        for (int j = 0; j < 32; ++j)
            acc[j] = fmaf(w2[(j1 + j) * HRDIM + k], xk, acc[j]);
    }
    __syncthreads();
    #pragma unroll
    for (int j = 0; j < 32; ++j) H[j1 + j][lane] = fmaxf(acc[j], 0.f);
    __syncthreads();

    if (wv == 0 && n0 < NN) {
        float l0 = b3[0], l1 = b3[1];
        #pragma unroll 8
        for (int k = 0; k < HRDIM; ++k) {
            float hk = H[k][lane];
            l0 = fmaf(w3[k],         hk, l0);
            l1 = fmaf(w3[HRDIM + k], hk, l1);
        }
        float mx = fmaxf(l0, l1);
        float e0 = __expf(l0 - mx), e1 = __expf(l1 - mx);
        float inv = 1.f / (e0 + e1);
        out[2 * n + 0] = e0 * inv;
        out[2 * n + 1] = e1 * inv;
    }
}

// ---------- host ----------
extern "C" void kernel_launch(void* const* d_in, const int* in_sizes, int n_in,
                              void* d_out, int out_size, void* d_ws, size_t ws_size,
                              hipStream_t stream)
{
    // ws layout — 10,880,000 f32 = 43.52 MB
    float* var_h = (float*)d_ws;          //   640,000 f32 [NN,64]
    float* fac_h = var_h + 640000;        // 5,120,000 f32 [NF,64]
    float* nm    = fac_h + 5120000;       // 5,120,000 f32 [NF,64] shared accum
                                          //   (var phase uses rows 0..NN-1)

    const int*   f2v_row  = (const int*)d_in[0];
    const int*   f2v_col  = (const int*)d_in[1];
    const int*   v2f_row  = (const int*)d_in[2];
    const int*   v2f_col  = (const int*)d_in[3];
    const float* f2v_feat = (const float*)d_in[4];
    const float* v2f_feat = (const float*)d_in[5];
    const float* W[26];
    for (int j = 0; j < 26; ++j) W[j] = (const float*)d_in[6 + j];
    // W: 0..5 f2v MLP, 6..11 v2f MLP, 12..15 gf GRU, 16..19 gv GRU, 20..25 readout

    k_zero<<<512, 256, 0, stream>>>(var_h, 640000 + 5120000 + 5120000);

    for (int s = 0; s < NSTEPS; ++s) {
        // fac -> var messages into nm[node]; var GRU
        k_edge_mlp<<<NE / 64, 256, 0, stream>>>(
            fac_h, var_h, f2v_row, f2v_col, f2v_feat,
            W[0], W[1], W[2], W[3], W[4], W[5], nm);
        k_gru<<<(NN + 63) / 64, 256, 0, stream>>>(
            nm, W[12], W[13], W[14], W[15], var_h, NN);
        // var -> fac messages into nm[factor]; fac GRU
        k_edge_mlp<<<NE / 64, 256, 0, stream>>>(
            var_h, fac_h, v2f_row, v2f_col, v2f_feat,
            W[6], W[7], W[8], W[9], W[10], W[11], nm);
        k_gru<<<(NF + 63) / 64, 256, 0, stream>>>(
            nm, W[16], W[17], W[18], W[19], fac_h, NF);
    }
    k_readout<<<(NN + 63) / 64, 256, 0, stream>>>(
        var_h, W[20], W[21], W[22], W[23], W[24], W[25],
        (float*)d_out);
}

// Round 12
// 6682.510 us; speedup vs baseline: 4.4708x; 1.2300x over previous
//
#include <hip/hip_runtime.h>

// Problem constants (fixed by reference setup)
#define NN     10000      // variable nodes
#define NF     80000      // factors
#define NE     160000     // directed edges per direction
#define SDIM   64         // state dim
#define HMDIM  128        // hidden (message MLP)
#define HRDIM  128        // hidden (readout)
#define KIN    136        // 2*S + 8
#define NSTEPS 5

static_assert(NE % 64 == 0, "edge grid exact");

// ---------- helpers ----------
static __device__ __forceinline__ float sigm(float x) {
    x = fminf(fmaxf(x, -30.f), 30.f);
    return 1.f / (1.f + __expf(-x));
}
static __device__ __forceinline__ float tanh_f(float x) {
    x = fminf(fmaxf(x, -15.f), 15.f);
    float t = __expf(2.f * x);
    return (t - 1.f) / (t + 1.f);
}

__global__ void k_zero(float* __restrict__ p, int n) {
    int i = blockIdx.x * blockDim.x + threadIdx.x;
    int stride = gridDim.x * blockDim.x;
    for (; i < n; i += stride) p[i] = 0.f;
}

// ---------- weight transpose (once per launch): dst[k][j] = src[j][k] ----------
#define NT 12
struct TArgs {
    const float* src[NT];
    float*       dst[NT];
    int          R[NT];    // rows (output dim j)
    int          C[NT];    // cols (input dim k)
};
__global__ void k_transpose(TArgs a) {
    const int b = blockIdx.x;
    const float* s = a.src[b];
    float* d = a.dst[b];
    const int R = a.R[b], C = a.C[b], n = R * C;
    for (int i = threadIdx.x; i < n; i += blockDim.x) {
        int r = i / C, c = i % C;
        d[c * R + r] = s[i];
    }
}

// ---------- tiled edge MLP + atomic scatter (transposed weights) ----------
// Block = 256 threads = 4 waves over the SAME 64 edges (lane = edge).
// Wave w owns j-chunk [32w,32w+32). Weights are k-major (wT[k][j]) so the 32
// per-k weights are CONSECUTIVE -> compiler emits wide s_load_dwordx8/x16
// (round-11 bottleneck: 4096 scattered s_load_dword per layer -> lgkmcnt
// stalls, VALUBusy 25%). Activations cross layers via LDS H[j][lane].
// Per-lane register state <= acc[32] -> no scratch.
__global__ __launch_bounds__(256, 3)
void k_edge_mlp(const float* __restrict__ hrow,    // f32 [*,64] indexed by rows[]
                const float* __restrict__ hcol,    // f32 [*,64] indexed by cols[]
                const int* __restrict__ rows, const int* __restrict__ cols,
                const float* __restrict__ feat,    // f32 [NE,4]
                const float* __restrict__ w1t,     // [KIN][128] k-major
                const float* __restrict__ b1,
                const float* __restrict__ w2t,     // [128][128] k-major
                const float* __restrict__ b2,
                const float* __restrict__ w3t,     // [128][64] k-major
                const float* __restrict__ b3,
                float* __restrict__ nm)
{
    __shared__ float H[HMDIM][64];               // 32 KB; [j][lane] 2-way free
    const int lane = threadIdx.x & 63;
    const int wv   = __builtin_amdgcn_readfirstlane(threadIdx.x >> 6);  // 0..3
    const int e = blockIdx.x * 64 + lane;        // grid exact: NE/64 blocks
    const int r = rows[e];
    const int c = cols[e];
    const float4* pr = (const float4*)(hrow + (size_t)r * SDIM);
    const float4* pc = (const float4*)(hcol + (size_t)c * SDIM);

    const int j1 = 32 * wv;                      // layer-1/2 chunk base
    float acc[32];
    #pragma unroll
    for (int j = 0; j < 32; ++j) acc[j] = b1[j1 + j];

    // ---- layer 1: k = 0..63 (hrow), streamed from global ----
    #pragma unroll 4
    for (int q = 0; q < 16; ++q) {
        float4 x4 = pr[q];
        const float* wa = w1t + (4 * q + 0) * HMDIM + j1;
        const float* wb = w1t + (4 * q + 1) * HMDIM + j1;
        const float* wc = w1t + (4 * q + 2) * HMDIM + j1;
        const float* wd = w1t + (4 * q + 3) * HMDIM + j1;
        #pragma unroll
        for (int j = 0; j < 32; ++j) {
            acc[j] = fmaf(wa[j], x4.x, acc[j]);
            acc[j] = fmaf(wb[j], x4.y, acc[j]);
            acc[j] = fmaf(wc[j], x4.z, acc[j]);
            acc[j] = fmaf(wd[j], x4.w, acc[j]);
        }
    }
    // k = 64..127 (hcol)
    #pragma unroll 4
    for (int q = 0; q < 16; ++q) {
        float4 x4 = pc[q];
        const float* wa = w1t + (64 + 4 * q + 0) * HMDIM + j1;
        const float* wb = w1t + (64 + 4 * q + 1) * HMDIM + j1;
        const float* wc = w1t + (64 + 4 * q + 2) * HMDIM + j1;
        const float* wd = w1t + (64 + 4 * q + 3) * HMDIM + j1;
        #pragma unroll
        for (int j = 0; j < 32; ++j) {
            acc[j] = fmaf(wa[j], x4.x, acc[j]);
            acc[j] = fmaf(wb[j], x4.y, acc[j]);
            acc[j] = fmaf(wc[j], x4.z, acc[j]);
            acc[j] = fmaf(wd[j], x4.w, acc[j]);
        }
    }
    // k = 128..135 (feat[r], feat[c])
    {
        float4 fr = *(const float4*)(feat + (size_t)r * 4);
        float4 fc = *(const float4*)(feat + (size_t)c * 4);
        float xf[8] = { fr.x, fr.y, fr.z, fr.w, fc.x, fc.y, fc.z, fc.w };
        #pragma unroll
        for (int kk = 0; kk < 8; ++kk) {
            const float* wr = w1t + (128 + kk) * HMDIM + j1;
            float xk = xf[kk];
            #pragma unroll
            for (int j = 0; j < 32; ++j) acc[j] = fmaf(wr[j], xk, acc[j]);
        }
    }
    #pragma unroll
    for (int j = 0; j < 32; ++j) H[j1 + j][lane] = fmaxf(acc[j], 0.f);
    __syncthreads();

    // ---- layer 2: stream h1 from LDS; wide scalar weight loads per k ----
    #pragma unroll
    for (int j = 0; j < 32; ++j) acc[j] = b2[j1 + j];
    #pragma unroll 4
    for (int k = 0; k < HMDIM; ++k) {
        float xk = H[k][lane];
        const float* wr = w2t + k * HMDIM + j1;
        #pragma unroll
        for (int j = 0; j < 32; ++j)
            acc[j] = fmaf(wr[j], xk, acc[j]);
    }
    __syncthreads();                             // all reads of h1 done
    #pragma unroll
    for (int j = 0; j < 32; ++j) H[j1 + j][lane] = fmaxf(acc[j], 0.f);
    __syncthreads();

    // ---- layer 3: wave computes j in [16wv,16wv+16); atomic into nm[c] ----
    {
        const int j3 = 16 * wv;
        float a3[16];
        #pragma unroll
        for (int j = 0; j < 16; ++j) a3[j] = b3[j3 + j];
        #pragma unroll 4
        for (int k = 0; k < HMDIM; ++k) {
            float xk = H[k][lane];
            const float* wr = w3t + k * 64 + j3;
            #pragma unroll
            for (int j = 0; j < 16; ++j)
                a3[j] = fmaf(wr[j], xk, a3[j]);
        }
        float* no = nm + (size_t)c * 64 + j3;
        #pragma unroll
        for (int j = 0; j < 16; ++j) atomicAdd(&no[j], a3[j]);
    }
}

// ---------- GRU: 64 rows/block, 4 waves; transposed weights ----------
__global__ __launch_bounds__(256, 3)
void k_gru(float* __restrict__ nm,
           const float* __restrict__ wiht,   // [64][192] k-major
           const float* __restrict__ whht,   // [64][192] k-major
           const float* __restrict__ bih, const float* __restrict__ bhh,
           float* __restrict__ hst, int count)
{
    __shared__ float M[SDIM][64];                // 16 KB
    __shared__ float Hs[SDIM][64];               // 16 KB
    const int lane = threadIdx.x & 63;
    const int wv   = __builtin_amdgcn_readfirstlane(threadIdx.x >> 6);
    const int row0 = blockIdx.x * 64 + lane;
    const int row  = row0 < count ? row0 : count - 1;
    const float4* m4 = (const float4*)(nm + (size_t)row * 64);
    const float4* h4 = (const float4*)(hst + (size_t)row * 64);

    #pragma unroll
    for (int qq = 0; qq < 4; ++qq) {
        int q = 4 * wv + qq;
        float4 tm = m4[q], th = h4[q];
        M[4*q+0][lane] = tm.x; M[4*q+1][lane] = tm.y;
        M[4*q+2][lane] = tm.z; M[4*q+3][lane] = tm.w;
        Hs[4*q+0][lane] = th.x; Hs[4*q+1][lane] = th.y;
        Hs[4*q+2][lane] = th.z; Hs[4*q+3][lane] = th.w;
    }
    __syncthreads();

    const int j0 = 16 * wv;                      // this wave's 16 outputs
    for (int jc = 0; jc < 16; jc += 4) {
        const int jb = j0 + jc;
        float air[4], aiz[4], ain[4], ahr[4], ahz[4], ahn[4];
        #pragma unroll
        for (int jj = 0; jj < 4; ++jj) {
            int j = jb + jj;
            air[jj] = bih[j];       aiz[jj] = bih[64 + j];  ain[jj] = bih[128 + j];
            ahr[jj] = bhh[j];       ahz[jj] = bhh[64 + j];  ahn[jj] = bhh[128 + j];
        }
        #pragma unroll 4
        for (int k = 0; k < SDIM; ++k) {
            float xk = M[k][lane], hk = Hs[k][lane];
            const float* wi = wiht + k * 192;
            const float* wh = whht + k * 192;
            #pragma unroll
            for (int jj = 0; jj < 4; ++jj) {
                int j = jb + jj;
                air[jj] = fmaf(wi[j],       xk, air[jj]);
                aiz[jj] = fmaf(wi[64 + j],  xk, aiz[jj]);
                ain[jj] = fmaf(wi[128 + j], xk, ain[jj]);
                ahr[jj] = fmaf(wh[j],       hk, ahr[jj]);
                ahz[jj] = fmaf(wh[64 + j],  hk, ahz[jj]);
                ahn[jj] = fmaf(wh[128 + j], hk, ahn[jj]);
            }
        }
        if (row0 < count) {
            float hn[4];
            #pragma unroll
            for (int jj = 0; jj < 4; ++jj) {
                int j = jb + jj;
                float r = sigm(air[jj] + ahr[jj]);
                float z = sigm(aiz[jj] + ahz[jj]);
                float t = tanh_f(ain[jj] + r * ahn[jj]);
                hn[jj] = (1.f - z) * t + z * Hs[j][lane];
            }
            *(float4*)(hst + (size_t)row * 64 + jb) =
                make_float4(hn[0], hn[1], hn[2], hn[3]);
        }
    }
    if (row0 < count) {
        float4* mo = (float4*)(nm + (size_t)row * 64);
        #pragma unroll
        for (int qq = 0; qq < 4; ++qq)
            mo[4 * wv + qq] = make_float4(0.f, 0.f, 0.f, 0.f);
    }
}

// ---------- readout: tiled; transposed weights; softmax -> f32 ----------
__global__ __launch_bounds__(256, 3)
void k_readout(const float* __restrict__ vh,
               const float* __restrict__ w1t,    // [64][128] k-major
               const float* __restrict__ b1,
               const float* __restrict__ w2t,    // [128][128] k-major
               const float* __restrict__ b2,
               const float* __restrict__ w3, const float* __restrict__ b3,
               float* __restrict__ out)
{
    __shared__ float H[HRDIM][64];               // 32 KB
    const int lane = threadIdx.x & 63;
    const int wv   = __builtin_amdgcn_readfirstlane(threadIdx.x >> 6);
    const int n0 = blockIdx.x * 64 + lane;
    const int n  = n0 < NN ? n0 : NN - 1;
    const float4* px = (const float4*)(vh + (size_t)n * 64);

    const int j1 = 32 * wv;
    float acc[32];
    #pragma unroll
    for (int j = 0; j < 32; ++j) acc[j] = b1[j1 + j];
    #pragma unroll 4
    for (int q = 0; q < 16; ++q) {
        float4 x4 = px[q];
        const float* wa = w1t + (4 * q + 0) * HRDIM + j1;
        const float* wb = w1t + (4 * q + 1) * HRDIM + j1;
        const float* wc = w1t + (4 * q + 2) * HRDIM + j1;
        const float* wd = w1t + (4 * q + 3) * HRDIM + j1;
        #pragma unroll
        for (int j = 0; j < 32; ++j) {
            acc[j] = fmaf(wa[j], x4.x, acc[j]);
            acc[j] = fmaf(wb[j], x4.y, acc[j]);
            acc[j] = fmaf(wc[j], x4.z, acc[j]);
            acc[j] = fmaf(wd[j], x4.w, acc[j]);
        }
    }
    #pragma unroll
    for (int j = 0; j < 32; ++j) H[j1 + j][lane] = fmaxf(acc[j], 0.f);
    __syncthreads();

    #pragma unroll
    for (int j = 0; j < 32; ++j) acc[j] = b2[j1 + j];
    #pragma unroll 4
    for (int k = 0; k < HRDIM; ++k) {
        float xk = H[k][lane];
        const float* wr = w2t + k * HRDIM + j1;
        #pragma unroll
        for (int j = 0; j < 32; ++j)
            acc[j] = fmaf(wr[j], xk, acc[j]);
    }
    __syncthreads();
    #pragma unroll
    for (int j = 0; j < 32; ++j) H[j1 + j][lane] = fmaxf(acc[j], 0.f);
    __syncthreads();

    if (wv == 0 && n0 < NN) {
        float l0 = b3[0], l1 = b3[1];
        #pragma unroll 8
        for (int k = 0; k < HRDIM; ++k) {
            float hk = H[k][lane];
            l0 = fmaf(w3[k],         hk, l0);
            l1 = fmaf(w3[HRDIM + k], hk, l1);
        }
        float mx = fmaxf(l0, l1);
        float e0 = __expf(l0 - mx), e1 = __expf(l1 - mx);
        float inv = 1.f / (e0 + e1);
        out[2 * n + 0] = e0 * inv;
        out[2 * n + 1] = e1 * inv;
    }
}

// ---------- host ----------
extern "C" void kernel_launch(void* const* d_in, const int* in_sizes, int n_in,
                              void* d_out, int out_size, void* d_ws, size_t ws_size,
                              hipStream_t stream)
{
    // ws layout — 10,880,000 + 157,696 f32 = 44.15 MB (R1 ran at 44.9 MB)
    float* var_h = (float*)d_ws;          //   640,000 f32 [NN,64]
    float* fac_h = var_h + 640000;        // 5,120,000 f32 [NF,64]
    float* nm    = fac_h + 5120000;       // 5,120,000 f32 [NF,64] shared accum
    float* wts   = nm + 5120000;          //   157,696 f32 transposed weights

    const int*   f2v_row  = (const int*)d_in[0];
    const int*   f2v_col  = (const int*)d_in[1];
    const int*   v2f_row  = (const int*)d_in[2];
    const int*   v2f_col  = (const int*)d_in[3];
    const float* f2v_feat = (const float*)d_in[4];
    const float* v2f_feat = (const float*)d_in[5];
    const float* W[26];
    for (int j = 0; j < 26; ++j) W[j] = (const float*)d_in[6 + j];
    // W: 0..5 f2v MLP (w1,b1,w2,b2,w3,b3), 6..11 v2f MLP,
    //    12..15 gf GRU (wih,whh,bih,bhh), 16..19 gv GRU, 20..25 readout

    // transposed copies: [k][j] layouts
    TArgs ta;
    float* T[NT];
    {
        // idx: 0 w1f,1 w2f,2 w3f, 3 w1v,4 w2v,5 w3v,
        //      6 gf_wih,7 gf_whh, 8 gv_wih,9 gv_whh, 10 ro_w1,11 ro_w2
        const float* src[NT] = { W[0], W[2], W[4], W[6], W[8], W[10],
                                 W[12], W[13], W[16], W[17], W[20], W[22] };
        int R[NT] = { HMDIM, HMDIM, SDIM,  HMDIM, HMDIM, SDIM,
                      192,   192,   192,   192,   HRDIM, HRDIM };
        int C[NT] = { KIN,   HMDIM, HMDIM, KIN,   HMDIM, HMDIM,
                      SDIM,  SDIM,  SDIM,  SDIM,  SDIM,  HRDIM };
        size_t off = 0;
        for (int t = 0; t < NT; ++t) {
            ta.src[t] = src[t]; ta.R[t] = R[t]; ta.C[t] = C[t];
            T[t] = wts + off; ta.dst[t] = T[t];
            off += (size_t)R[t] * C[t];
        }
    }
    k_transpose<<<NT, 256, 0, stream>>>(ta);
    k_zero<<<512, 256, 0, stream>>>(var_h, 640000 + 5120000 + 5120000);

    for (int s = 0; s < NSTEPS; ++s) {
        // fac -> var messages into nm[node]; var GRU
        k_edge_mlp<<<NE / 64, 256, 0, stream>>>(
            fac_h, var_h, f2v_row, f2v_col, f2v_feat,
            T[0], W[1], T[1], W[3], T[2], W[5], nm);
        k_gru<<<(NN + 63) / 64, 256, 0, stream>>>(
            nm, T[6], T[7], W[14], W[15], var_h, NN);
        // var -> fac messages into nm[factor]; fac GRU
        k_edge_mlp<<<NE / 64, 256, 0, stream>>>(
            var_h, fac_h, v2f_row, v2f_col, v2f_feat,
            T[3], W[7], T[4], W[9], T[5], W[11], nm);
        k_gru<<<(NF + 63) / 64, 256, 0, stream>>>(
            nm, T[8], T[9], W[18], W[19], fac_h, NF);
    }
    k_readout<<<(NN + 63) / 64, 256, 0, stream>>>(
        var_h, T[10], W[21], T[11], W[23], W[24], W[25],
        (float*)d_out);
}

// Round 13
// 1696.911 us; speedup vs baseline: 17.6062x; 3.9380x over previous
//
#include <hip/hip_runtime.h>

// Problem constants (fixed by reference setup)
#define NN     10000      // variable nodes
#define NF     80000      // factors
#define NE     160000     // directed edges per direction
#define SDIM   64         // state dim
#define HMDIM  128        // hidden (message MLP)
#define HRDIM  128        // hidden (readout)
#define KIN    136        // 2*S + 8
#define NSTEPS 5

static_assert(NE % 64 == 0, "edge grid exact");

typedef __attribute__((ext_vector_type(8))) short short8;   // 8 bf16 = 4 VGPRs
typedef __attribute__((ext_vector_type(4))) float f32x4;    // MFMA C/D

// ---------- helpers ----------
static __device__ __forceinline__ float bf2f(unsigned short u) {
    return __uint_as_float(((unsigned int)u) << 16);
}
static __device__ __forceinline__ unsigned short f2bf(float f) {
    unsigned int u = __float_as_uint(f);
    u += 0x7fffu + ((u >> 16) & 1u);          // round-to-nearest-even
    return (unsigned short)(u >> 16);
}
static __device__ __forceinline__ float sigm(float x) {
    x = fminf(fmaxf(x, -30.f), 30.f);
    return 1.f / (1.f + __expf(-x));
}
static __device__ __forceinline__ float tanh_f(float x) {
    x = fminf(fmaxf(x, -15.f), 15.f);
    float t = __expf(2.f * x);
    return (t - 1.f) / (t + 1.f);
}
// split f32 -> bf16 hi + bf16 lo (x ~= hi + lo, ~16 mantissa bits kept)
static __device__ __forceinline__ void split8(const float* x, short8& hi, short8& lo) {
    #pragma unroll
    for (int i = 0; i < 8; ++i) {
        unsigned short h = f2bf(x[i]);
        hi[i] = (short)h;
        lo[i] = (short)f2bf(x[i] - bf2f(h));
    }
}

__global__ void k_zero(float* __restrict__ p, int n) {
    int i = blockIdx.x * blockDim.x + threadIdx.x;
    int stride = gridDim.x * blockDim.x;
    for (; i < n; i += stride) p[i] = 0.f;
}

// ---------- weight transpose for GRU/readout (dst[k][j] = src[j][k]) ----------
#define NTR 6
struct TArgs {
    const float* src[NTR];
    float*       dst[NTR];
    int          R[NTR];   // rows (output dim j)
    int          C[NTR];   // cols (input dim k)
};
__global__ void k_transpose(TArgs a) {
    const int b = blockIdx.x;
    const float* s = a.src[b];
    float* d = a.dst[b];
    const int R = a.R[b], C = a.C[b], n = R * C;
    for (int i = threadIdx.x; i < n; i += blockDim.x) {
        int r = i / C, c = i % C;
        d[c * R + r] = s[i];
    }
}

// ---------- pack MLP weights into B-fragment streams (hi/lo bf16) ----------
// Stream element idx = ((ck*NT + tn)*64 + lane)*8 + j holds
// B[k = ck*32 + (lane>>4)*8 + j][n = tn*16 + (lane&15)] = w[n][k] (0 if k>=K).
#define NPK 6
struct PArgs {
    const float*    src[NPK];
    unsigned short* hi[NPK];
    unsigned short* lo[NPK];
    int             N[NPK], K[NPK], CK[NPK];
};
__global__ void k_pack(PArgs a) {
    const int b = blockIdx.x;
    const float* s = a.src[b];
    unsigned short* ph = a.hi[b];
    unsigned short* pl = a.lo[b];
    const int N = a.N[b], K = a.K[b], CK = a.CK[b];
    const int NT = N >> 4;
    const int total = NT * CK * 512;
    for (int i = threadIdx.x; i < total; i += blockDim.x) {
        int j    = i & 7;
        int ln   = (i >> 3) & 63;
        int tile = i >> 9;
        int tn   = tile % NT;
        int ck   = tile / NT;
        int k = ck * 32 + ((ln >> 4) * 8) + j;
        int n = tn * 16 + (ln & 15);
        float f = (k < K) ? s[n * K + k] : 0.f;
        unsigned short h = f2bf(f);
        ph[i] = h;
        pl[i] = f2bf(f - bf2f(h));
    }
}

// ---------- MFMA edge MLP + atomic scatter ----------
// Block = 64 edges, 256 threads = 4 waves. Wave w owns edges [16w,16w+16)
// as the MFMA M-tile and computes ALL N via 16x16x32 bf16 MFMA with hi/lo
// split (3 MFMAs per tile ~ fp32 accuracy). B-frags come pre-packed (one
// coalesced 16B load each). Inter-layer acts go через LDS H (bf16 hi/lo),
// rows are wave-private -> NO barriers anywhere.
__global__ __launch_bounds__(256, 3)
void k_edge_mfma(const float* __restrict__ hrow, const float* __restrict__ hcol,
                 const int* __restrict__ rows, const int* __restrict__ cols,
                 const float* __restrict__ feat,
                 const unsigned short* __restrict__ w1h, const unsigned short* __restrict__ w1l,
                 const unsigned short* __restrict__ w2h, const unsigned short* __restrict__ w2l,
                 const unsigned short* __restrict__ w3h, const unsigned short* __restrict__ w3l,
                 const float* __restrict__ b1, const float* __restrict__ b2,
                 const float* __restrict__ b3,
                 float* __restrict__ nm)
{
    __shared__ unsigned short Hhi[64][136];   // stride 272B: 16B-aligned rows
    __shared__ unsigned short Hlo[64][136];   // 34 KB total
    const int lane = threadIdx.x & 63;
    const int wv   = threadIdx.x >> 6;        // 0..3
    const int quad = lane >> 4;               // 0..3
    const int col  = lane & 15;
    const int eA = blockIdx.x * 64 + wv * 16 + col;   // edge = A-frag row m
    const int r = rows[eA];
    const int c = cols[eA];

    f32x4 acc[8];
    #pragma unroll
    for (int t = 0; t < 8; ++t) acc[t] = (f32x4){0.f, 0.f, 0.f, 0.f};

    // ---- layer 1: K = 136 padded to 160 (5 chunks of 32) ----
    #pragma unroll
    for (int ck = 0; ck < 5; ++ck) {
        float xv[8];
        if (ck < 2) {
            const float4* p = (const float4*)(hrow + (size_t)r * 64 + ck * 32 + quad * 8);
            float4 A0 = p[0], A1 = p[1];
            xv[0]=A0.x; xv[1]=A0.y; xv[2]=A0.z; xv[3]=A0.w;
            xv[4]=A1.x; xv[5]=A1.y; xv[6]=A1.z; xv[7]=A1.w;
        } else if (ck < 4) {
            const float4* p = (const float4*)(hcol + (size_t)c * 64 + (ck - 2) * 32 + quad * 8);
            float4 A0 = p[0], A1 = p[1];
            xv[0]=A0.x; xv[1]=A0.y; xv[2]=A0.z; xv[3]=A0.w;
            xv[4]=A1.x; xv[5]=A1.y; xv[6]=A1.z; xv[7]=A1.w;
        } else {
            if (quad == 0) {
                float4 fr4 = *(const float4*)(feat + (size_t)r * 4);
                float4 fc4 = *(const float4*)(feat + (size_t)c * 4);
                xv[0]=fr4.x; xv[1]=fr4.y; xv[2]=fr4.z; xv[3]=fr4.w;
                xv[4]=fc4.x; xv[5]=fc4.y; xv[6]=fc4.z; xv[7]=fc4.w;
            } else {
                #pragma unroll
                for (int i = 0; i < 8; ++i) xv[i] = 0.f;
            }
        }
        short8 ahi, alo;
        split8(xv, ahi, alo);
        const unsigned short* bh = w1h + (size_t)(ck * 8) * 512 + lane * 8;
        const unsigned short* bl = w1l + (size_t)(ck * 8) * 512 + lane * 8;
        #pragma unroll
        for (int tn = 0; tn < 8; ++tn) {
            short8 bhi = *(const short8*)(bh + tn * 512);
            short8 blo = *(const short8*)(bl + tn * 512);
            acc[tn] = __builtin_amdgcn_mfma_f32_16x16x32_bf16(ahi, bhi, acc[tn], 0, 0, 0);
            acc[tn] = __builtin_amdgcn_mfma_f32_16x16x32_bf16(ahi, blo, acc[tn], 0, 0, 0);
            acc[tn] = __builtin_amdgcn_mfma_f32_16x16x32_bf16(alo, bhi, acc[tn], 0, 0, 0);
        }
    }
    // epilogue 1: bias + relu -> H (bf16 hi/lo), wave-private rows
    #pragma unroll
    for (int tn = 0; tn < 8; ++tn) {
        float bias = b1[tn * 16 + col];
        #pragma unroll
        for (int rr = 0; rr < 4; ++rr) {
            float v = fmaxf(acc[tn][rr] + bias, 0.f);
            int m = wv * 16 + quad * 4 + rr;
            unsigned short h = f2bf(v);
            Hhi[m][tn * 16 + col] = h;
            Hlo[m][tn * 16 + col] = f2bf(v - bf2f(h));
        }
    }

    // ---- layer 2: K = 128 (4 chunks) ----
    #pragma unroll
    for (int t = 0; t < 8; ++t) acc[t] = (f32x4){0.f, 0.f, 0.f, 0.f};
    {
        const int m = wv * 16 + col;
        #pragma unroll
        for (int ck = 0; ck < 4; ++ck) {
            short8 ahi = *(const short8*)(&Hhi[m][ck * 32 + quad * 8]);
            short8 alo = *(const short8*)(&Hlo[m][ck * 32 + quad * 8]);
            const unsigned short* bh = w2h + (size_t)(ck * 8) * 512 + lane * 8;
            const unsigned short* bl = w2l + (size_t)(ck * 8) * 512 + lane * 8;
            #pragma unroll
            for (int tn = 0; tn < 8; ++tn) {
                short8 bhi = *(const short8*)(bh + tn * 512);
                short8 blo = *(const short8*)(bl + tn * 512);
                acc[tn] = __builtin_amdgcn_mfma_f32_16x16x32_bf16(ahi, bhi, acc[tn], 0, 0, 0);
                acc[tn] = __builtin_amdgcn_mfma_f32_16x16x32_bf16(ahi, blo, acc[tn], 0, 0, 0);
                acc[tn] = __builtin_amdgcn_mfma_f32_16x16x32_bf16(alo, bhi, acc[tn], 0, 0, 0);
            }
        }
    }
    // epilogue 2: bias + relu -> H (reads of layer-2 A already done, in-order)
    #pragma unroll
    for (int tn = 0; tn < 8; ++tn) {
        float bias = b2[tn * 16 + col];
        #pragma unroll
        for (int rr = 0; rr < 4; ++rr) {
            float v = fmaxf(acc[tn][rr] + bias, 0.f);
            int m = wv * 16 + quad * 4 + rr;
            unsigned short h = f2bf(v);
            Hhi[m][tn * 16 + col] = h;
            Hlo[m][tn * 16 + col] = f2bf(v - bf2f(h));
        }
    }

    // ---- layer 3: N = 64 (4 tiles), K = 128 ----
    f32x4 a3[4];
    #pragma unroll
    for (int t = 0; t < 4; ++t) a3[t] = (f32x4){0.f, 0.f, 0.f, 0.f};
    {
        const int m = wv * 16 + col;
        #pragma unroll
        for (int ck = 0; ck < 4; ++ck) {
            short8 ahi = *(const short8*)(&Hhi[m][ck * 32 + quad * 8]);
            short8 alo = *(const short8*)(&Hlo[m][ck * 32 + quad * 8]);
            const unsigned short* bh = w3h + (size_t)(ck * 4) * 512 + lane * 8;
            const unsigned short* bl = w3l + (size_t)(ck * 4) * 512 + lane * 8;
            #pragma unroll
            for (int tn = 0; tn < 4; ++tn) {
                short8 bhi = *(const short8*)(bh + tn * 512);
                short8 blo = *(const short8*)(bl + tn * 512);
                a3[tn] = __builtin_amdgcn_mfma_f32_16x16x32_bf16(ahi, bhi, a3[tn], 0, 0, 0);
                a3[tn] = __builtin_amdgcn_mfma_f32_16x16x32_bf16(ahi, blo, a3[tn], 0, 0, 0);
                a3[tn] = __builtin_amdgcn_mfma_f32_16x16x32_bf16(alo, bhi, a3[tn], 0, 0, 0);
            }
        }
    }
    // epilogue 3: bias + atomic scatter into nm[cols[edge]]
    int cc[4];
    #pragma unroll
    for (int rr = 0; rr < 4; ++rr)
        cc[rr] = cols[blockIdx.x * 64 + wv * 16 + quad * 4 + rr];
    #pragma unroll
    for (int tn = 0; tn < 4; ++tn) {
        float bias = b3[tn * 16 + col];
        #pragma unroll
        for (int rr = 0; rr < 4; ++rr)
            atomicAdd(&nm[(size_t)cc[rr] * 64 + tn * 16 + col], a3[tn][rr] + bias);
    }
}

// ---------- GRU: 64 rows/block, 4 waves; transposed weights (unchanged) ----------
__global__ __launch_bounds__(256, 3)
void k_gru(float* __restrict__ nm,
           const float* __restrict__ wiht,   // [64][192] k-major
           const float* __restrict__ whht,   // [64][192] k-major
           const float* __restrict__ bih, const float* __restrict__ bhh,
           float* __restrict__ hst, int count)
{
    __shared__ float M[SDIM][64];
    __shared__ float Hs[SDIM][64];
    const int lane = threadIdx.x & 63;
    const int wv   = __builtin_amdgcn_readfirstlane(threadIdx.x >> 6);
    const int row0 = blockIdx.x * 64 + lane;
    const int row  = row0 < count ? row0 : count - 1;
    const float4* m4 = (const float4*)(nm + (size_t)row * 64);
    const float4* h4 = (const float4*)(hst + (size_t)row * 64);

    #pragma unroll
    for (int qq = 0; qq < 4; ++qq) {
        int q = 4 * wv + qq;
        float4 tm = m4[q], th = h4[q];
        M[4*q+0][lane] = tm.x; M[4*q+1][lane] = tm.y;
        M[4*q+2][lane] = tm.z; M[4*q+3][lane] = tm.w;
        Hs[4*q+0][lane] = th.x; Hs[4*q+1][lane] = th.y;
        Hs[4*q+2][lane] = th.z; Hs[4*q+3][lane] = th.w;
    }
    __syncthreads();

    const int j0 = 16 * wv;
    for (int jc = 0; jc < 16; jc += 4) {
        const int jb = j0 + jc;
        float air[4], aiz[4], ain[4], ahr[4], ahz[4], ahn[4];
        #pragma unroll
        for (int jj = 0; jj < 4; ++jj) {
            int j = jb + jj;
            air[jj] = bih[j];       aiz[jj] = bih[64 + j];  ain[jj] = bih[128 + j];
            ahr[jj] = bhh[j];       ahz[jj] = bhh[64 + j];  ahn[jj] = bhh[128 + j];
        }
        #pragma unroll 4
        for (int k = 0; k < SDIM; ++k) {
            float xk = M[k][lane], hk = Hs[k][lane];
            const float* wi = wiht + k * 192;
            const float* wh = whht + k * 192;
            #pragma unroll
            for (int jj = 0; jj < 4; ++jj) {
                int j = jb + jj;
                air[jj] = fmaf(wi[j],       xk, air[jj]);
                aiz[jj] = fmaf(wi[64 + j],  xk, aiz[jj]);
                ain[jj] = fmaf(wi[128 + j], xk, ain[jj]);
                ahr[jj] = fmaf(wh[j],       hk, ahr[jj]);
                ahz[jj] = fmaf(wh[64 + j],  hk, ahz[jj]);
                ahn[jj] = fmaf(wh[128 + j], hk, ahn[jj]);
            }
        }
        if (row0 < count) {
            float hn[4];
            #pragma unroll
            for (int jj = 0; jj < 4; ++jj) {
                int j = jb + jj;
                float r = sigm(air[jj] + ahr[jj]);
                float z = sigm(aiz[jj] + ahz[jj]);
                float t = tanh_f(ain[jj] + r * ahn[jj]);
                hn[jj] = (1.f - z) * t + z * Hs[j][lane];
            }
            *(float4*)(hst + (size_t)row * 64 + jb) =
                make_float4(hn[0], hn[1], hn[2], hn[3]);
        }
    }
    if (row0 < count) {
        float4* mo = (float4*)(nm + (size_t)row * 64);
        #pragma unroll
        for (int qq = 0; qq < 4; ++qq)
            mo[4 * wv + qq] = make_float4(0.f, 0.f, 0.f, 0.f);
    }
}

// ---------- readout (unchanged) ----------
__global__ __launch_bounds__(256, 3)
void k_readout(const float* __restrict__ vh,
               const float* __restrict__ w1t,    // [64][128] k-major
               const float* __restrict__ b1,
               const float* __restrict__ w2t,    // [128][128] k-major
               const float* __restrict__ b2,
               const float* __restrict__ w3, const float* __restrict__ b3,
               float* __restrict__ out)
{
    __shared__ float H[HRDIM][64];
    const int lane = threadIdx.x & 63;
    const int wv   = __builtin_amdgcn_readfirstlane(threadIdx.x >> 6);
    const int n0 = blockIdx.x * 64 + lane;
    const int n  = n0 < NN ? n0 : NN - 1;
    const float4* px = (const float4*)(vh + (size_t)n * 64);

    const int j1 = 32 * wv;
    float acc[32];
    #pragma unroll
    for (int j = 0; j < 32; ++j) acc[j] = b1[j1 + j];
    #pragma unroll 4
    for (int q = 0; q < 16; ++q) {
        float4 x4 = px[q];
        const float* wa = w1t + (4 * q + 0) * HRDIM + j1;
        const float* wb = w1t + (4 * q + 1) * HRDIM + j1;
        const float* wc = w1t + (4 * q + 2) * HRDIM + j1;
        const float* wd = w1t + (4 * q + 3) * HRDIM + j1;
        #pragma unroll
        for (int j = 0; j < 32; ++j) {
            acc[j] = fmaf(wa[j], x4.x, acc[j]);
            acc[j] = fmaf(wb[j], x4.y, acc[j]);
            acc[j] = fmaf(wc[j], x4.z, acc[j]);
            acc[j] = fmaf(wd[j], x4.w, acc[j]);
        }
    }
    #pragma unroll
    for (int j = 0; j < 32; ++j) H[j1 + j][lane] = fmaxf(acc[j], 0.f);
    __syncthreads();

    #pragma unroll
    for (int j = 0; j < 32; ++j) acc[j] = b2[j1 + j];
    #pragma unroll 4
    for (int k = 0; k < HRDIM; ++k) {
        float xk = H[k][lane];
        const float* wr = w2t + k * HRDIM + j1;
        #pragma unroll
        for (int j = 0; j < 32; ++j)
            acc[j] = fmaf(wr[j], xk, acc[j]);
    }
    __syncthreads();
    #pragma unroll
    for (int j = 0; j < 32; ++j) H[j1 + j][lane] = fmaxf(acc[j], 0.f);
    __syncthreads();

    if (wv == 0 && n0 < NN) {
        float l0 = b3[0], l1 = b3[1];
        #pragma unroll 8
        for (int k = 0; k < HRDIM; ++k) {
            float hk = H[k][lane];
            l0 = fmaf(w3[k],         hk, l0);
            l1 = fmaf(w3[HRDIM + k], hk, l1);
        }
        float mx = fmaxf(l0, l1);
        float e0 = __expf(l0 - mx), e1 = __expf(l1 - mx);
        float inv = 1.f / (e0 + e1);
        out[2 * n + 0] = e0 * inv;
        out[2 * n + 1] = e1 * inv;
    }
}

// ---------- host ----------
extern "C" void kernel_launch(void* const* d_in, const int* in_sizes, int n_in,
                              void* d_out, int out_size, void* d_ws, size_t ws_size,
                              hipStream_t stream)
{
    // ws layout (f32 units):
    //   var_h 640,000 | fac_h 5,120,000 | nm 5,120,000 | gru/ro transposed 73,728
    //   | packed MLP bf16 streams 90,112 f32-equiv  => total 11,043,840 f32 = 44.18 MB
    float* var_h = (float*)d_ws;
    float* fac_h = var_h + 640000;
    float* nm    = fac_h + 5120000;
    float* wts_t = nm + 5120000;                         // 73,728 f32
    unsigned short* pk = (unsigned short*)(wts_t + 73728); // 180,224 shorts

    const int*   f2v_row  = (const int*)d_in[0];
    const int*   f2v_col  = (const int*)d_in[1];
    const int*   v2f_row  = (const int*)d_in[2];
    const int*   v2f_col  = (const int*)d_in[3];
    const float* f2v_feat = (const float*)d_in[4];
    const float* v2f_feat = (const float*)d_in[5];
    const float* W[26];
    for (int j = 0; j < 26; ++j) W[j] = (const float*)d_in[6 + j];
    // W: 0..5 f2v MLP (w1,b1,w2,b2,w3,b3), 6..11 v2f MLP,
    //    12..15 gf GRU (wih,whh,bih,bhh), 16..19 gv GRU, 20..25 readout

    // transposed GRU/readout weights
    TArgs ta;
    float* T[NTR];
    {
        const float* src[NTR] = { W[12], W[13], W[16], W[17], W[20], W[22] };
        int R[NTR] = { 192, 192, 192, 192, HRDIM, HRDIM };
        int C[NTR] = { SDIM, SDIM, SDIM, SDIM, SDIM, HRDIM };
        size_t off = 0;
        for (int t = 0; t < NTR; ++t) {
            ta.src[t] = src[t]; ta.R[t] = R[t]; ta.C[t] = C[t];
            T[t] = wts_t + off; ta.dst[t] = T[t];
            off += (size_t)R[t] * C[t];
        }
    }
    // packed MLP B-frag streams: per direction w1(20480) w2(16384) w3(8192), hi+lo
    unsigned short* P[12]; // f2v: w1h,w1l,w2h,w2l,w3h,w3l ; v2f: same at +90112
    {
        size_t off = 0;
        int sz[3] = { 20480, 16384, 8192 };
        for (int d = 0; d < 2; ++d)
            for (int m = 0; m < 3; ++m) {
                P[d * 6 + m * 2 + 0] = pk + off; off += sz[m];
                P[d * 6 + m * 2 + 1] = pk + off; off += sz[m];
            }
    }
    PArgs pa;
    {
        const float* src[NPK] = { W[0], W[2], W[4], W[6], W[8], W[10] };
        int N[NPK]  = { HMDIM, HMDIM, SDIM,  HMDIM, HMDIM, SDIM };
        int K[NPK]  = { KIN,   HMDIM, HMDIM, KIN,   HMDIM, HMDIM };
        int CK[NPK] = { 5,     4,     4,     5,     4,     4 };
        int hiIdx[NPK] = { 0, 2, 4, 6, 8, 10 };
        for (int t = 0; t < NPK; ++t) {
            pa.src[t] = src[t]; pa.N[t] = N[t]; pa.K[t] = K[t]; pa.CK[t] = CK[t];
            pa.hi[t] = P[hiIdx[t]]; pa.lo[t] = P[hiIdx[t] + 1];
        }
    }
    k_transpose<<<NTR, 256, 0, stream>>>(ta);
    k_pack<<<NPK, 256, 0, stream>>>(pa);
    k_zero<<<512, 256, 0, stream>>>(var_h, 640000 + 5120000 + 5120000);

    for (int s = 0; s < NSTEPS; ++s) {
        // fac -> var messages into nm[node]; var GRU
        k_edge_mfma<<<NE / 64, 256, 0, stream>>>(
            fac_h, var_h, f2v_row, f2v_col, f2v_feat,
            P[0], P[1], P[2], P[3], P[4], P[5],
            W[1], W[3], W[5], nm);
        k_gru<<<(NN + 63) / 64, 256, 0, stream>>>(
            nm, T[0], T[1], W[14], W[15], var_h, NN);
        // var -> fac messages into nm[factor]; fac GRU
        k_edge_mfma<<<NE / 64, 256, 0, stream>>>(
            var_h, fac_h, v2f_row, v2f_col, v2f_feat,
            P[6], P[7], P[8], P[9], P[10], P[11],
            W[7], W[9], W[11], nm);
        k_gru<<<(NF + 63) / 64, 256, 0, stream>>>(
            nm, T[2], T[3], W[18], W[19], fac_h, NF);
    }
    k_readout<<<(NN + 63) / 64, 256, 0, stream>>>(
        var_h, T[4], W[21], T[5], W[23], W[24], W[25],
        (float*)d_out);
}

// Round 14
// 1692.411 us; speedup vs baseline: 17.6530x; 1.0027x over previous
//
#include <hip/hip_runtime.h>

// Problem constants (fixed by reference setup)
#define NN     10000      // variable nodes
#define NF     80000      // factors
#define NE     160000     // directed edges per direction
#define SDIM   64         // state dim
#define HMDIM  128        // hidden (message MLP)
#define HRDIM  128        // hidden (readout)
#define KIN    136        // 2*S + 8
#define NSTEPS 5

static_assert(NE % 64 == 0, "edge grid exact");

typedef __attribute__((ext_vector_type(8))) short short8;   // 8 bf16 = 4 VGPRs
typedef __attribute__((ext_vector_type(4))) float f32x4;    // MFMA C/D

// ---------- helpers ----------
static __device__ __forceinline__ float bf2f(unsigned short u) {
    return __uint_as_float(((unsigned int)u) << 16);
}
static __device__ __forceinline__ unsigned short f2bf(float f) {
    unsigned int u = __float_as_uint(f);
    u += 0x7fffu + ((u >> 16) & 1u);          // round-to-nearest-even
    return (unsigned short)(u >> 16);
}
static __device__ __forceinline__ float sigm(float x) {
    x = fminf(fmaxf(x, -30.f), 30.f);
    return 1.f / (1.f + __expf(-x));
}
static __device__ __forceinline__ float tanh_f(float x) {
    x = fminf(fmaxf(x, -15.f), 15.f);
    float t = __expf(2.f * x);
    return (t - 1.f) / (t + 1.f);
}
// split f32 -> bf16 hi + bf16 lo (x ~= hi + lo, ~16 mantissa bits kept)
static __device__ __forceinline__ void split8(const float* x, short8& hi, short8& lo) {
    #pragma unroll
    for (int i = 0; i < 8; ++i) {
        unsigned short h = f2bf(x[i]);
        hi[i] = (short)h;
        lo[i] = (short)f2bf(x[i] - bf2f(h));
    }
}

__global__ void k_zero(float* __restrict__ p, int n) {
    int i = blockIdx.x * blockDim.x + threadIdx.x;
    int stride = gridDim.x * blockDim.x;
    for (; i < n; i += stride) p[i] = 0.f;
}

// ---------- weight transpose for GRU/readout (dst[k][j] = src[j][k]) ----------
#define NTR 6
struct TArgs {
    const float* src[NTR];
    float*       dst[NTR];
    int          R[NTR];   // rows (output dim j)
    int          C[NTR];   // cols (input dim k)
};
__global__ void k_transpose(TArgs a) {
    const int b = blockIdx.x;
    const float* s = a.src[b];
    float* d = a.dst[b];
    const int R = a.R[b], C = a.C[b], n = R * C;
    for (int i = threadIdx.x; i < n; i += blockDim.x) {
        int r = i / C, c = i % C;
        d[c * R + r] = s[i];
    }
}

// ---------- pack MLP weights into B-fragment streams (hi/lo bf16) ----------
// Stream element idx = ((ck*NT + tn)*64 + lane)*8 + j holds
// B[k = ck*32 + (lane>>4)*8 + j][n = tn*16 + (lane&15)] = w[n][k] (0 if k>=K).
#define NPK 6
struct PArgs {
    const float*    src[NPK];
    unsigned short* hi[NPK];
    unsigned short* lo[NPK];
    int             N[NPK], K[NPK], CK[NPK];
};
__global__ void k_pack(PArgs a) {
    const int b = blockIdx.x;
    const float* s = a.src[b];
    unsigned short* ph = a.hi[b];
    unsigned short* pl = a.lo[b];
    const int N = a.N[b], K = a.K[b], CK = a.CK[b];
    const int NT = N >> 4;
    const int total = NT * CK * 512;
    for (int i = threadIdx.x; i < total; i += blockDim.x) {
        int j    = i & 7;
        int ln   = (i >> 3) & 63;
        int tile = i >> 9;
        int tn   = tile % NT;
        int ck   = tile / NT;
        int k = ck * 32 + ((ln >> 4) * 8) + j;
        int n = tn * 16 + (ln & 15);
        float f = (k < K) ? s[n * K + k] : 0.f;
        unsigned short h = f2bf(f);
        ph[i] = h;
        pl[i] = f2bf(f - bf2f(h));
    }
}

// ---------- MFMA edge MLP + atomic scatter (M=32 per wave) ----------
// Block = 64 edges, 128 threads = 2 waves. Wave w owns edges [32w,32w+32)
// as TWO 16-row M-tiles sharing every B-fragment load (round-13 bottleneck:
// 1.76 GB/dispatch of B-frag L2 traffic at 3 MFMAs per load pair; now 6
// MFMAs per pair, traffic halved). hi/lo split bf16: 3 MFMAs ~ fp32
// accuracy. Inter-layer acts in LDS (bf16 hi/lo), rows wave-private -> no
// barriers.
__global__ __launch_bounds__(128, 3)
void k_edge_mfma(const float* __restrict__ hrow, const float* __restrict__ hcol,
                 const int* __restrict__ rows, const int* __restrict__ cols,
                 const float* __restrict__ feat,
                 const unsigned short* __restrict__ w1h, const unsigned short* __restrict__ w1l,
                 const unsigned short* __restrict__ w2h, const unsigned short* __restrict__ w2l,
                 const unsigned short* __restrict__ w3h, const unsigned short* __restrict__ w3l,
                 const float* __restrict__ b1, const float* __restrict__ b2,
                 const float* __restrict__ b3,
                 float* __restrict__ nm)
{
    __shared__ unsigned short Hhi[64][136];   // stride 272B (17x16B): conflict-light
    __shared__ unsigned short Hlo[64][136];   // 34 KB total
    const int lane = threadIdx.x & 63;
    const int wv   = threadIdx.x >> 6;        // 0..1
    const int quad = lane >> 4;               // 0..3
    const int col  = lane & 15;
    int r[2], c[2];
    {
        int e0 = blockIdx.x * 64 + wv * 32 + col;
        r[0] = rows[e0];      c[0] = cols[e0];
        r[1] = rows[e0 + 16]; c[1] = cols[e0 + 16];
    }

    f32x4 acc[2][8];
    #pragma unroll
    for (int mt = 0; mt < 2; ++mt)
        #pragma unroll
        for (int t = 0; t < 8; ++t) acc[mt][t] = (f32x4){0.f, 0.f, 0.f, 0.f};

    // ---- layer 1: K = 136 padded to 160 (5 chunks of 32) ----
    #pragma unroll
    for (int ck = 0; ck < 5; ++ck) {
        short8 ahi[2], alo[2];
        #pragma unroll
        for (int mt = 0; mt < 2; ++mt) {
            float xv[8];
            if (ck < 2) {
                const float4* p = (const float4*)(hrow + (size_t)r[mt] * 64 + ck * 32 + quad * 8);
                float4 A0 = p[0], A1 = p[1];
                xv[0]=A0.x; xv[1]=A0.y; xv[2]=A0.z; xv[3]=A0.w;
                xv[4]=A1.x; xv[5]=A1.y; xv[6]=A1.z; xv[7]=A1.w;
            } else if (ck < 4) {
                const float4* p = (const float4*)(hcol + (size_t)c[mt] * 64 + (ck - 2) * 32 + quad * 8);
                float4 A0 = p[0], A1 = p[1];
                xv[0]=A0.x; xv[1]=A0.y; xv[2]=A0.z; xv[3]=A0.w;
                xv[4]=A1.x; xv[5]=A1.y; xv[6]=A1.z; xv[7]=A1.w;
            } else {
                if (quad == 0) {
                    float4 fr4 = *(const float4*)(feat + (size_t)r[mt] * 4);
                    float4 fc4 = *(const float4*)(feat + (size_t)c[mt] * 4);
                    xv[0]=fr4.x; xv[1]=fr4.y; xv[2]=fr4.z; xv[3]=fr4.w;
                    xv[4]=fc4.x; xv[5]=fc4.y; xv[6]=fc4.z; xv[7]=fc4.w;
                } else {
                    #pragma unroll
                    for (int i = 0; i < 8; ++i) xv[i] = 0.f;
                }
            }
            split8(xv, ahi[mt], alo[mt]);
        }
        const unsigned short* bh = w1h + (size_t)(ck * 8) * 512 + lane * 8;
        const unsigned short* bl = w1l + (size_t)(ck * 8) * 512 + lane * 8;
        #pragma unroll
        for (int tn = 0; tn < 8; ++tn) {
            short8 bhi = *(const short8*)(bh + tn * 512);
            short8 blo = *(const short8*)(bl + tn * 512);
            #pragma unroll
            for (int mt = 0; mt < 2; ++mt) {
                acc[mt][tn] = __builtin_amdgcn_mfma_f32_16x16x32_bf16(ahi[mt], bhi, acc[mt][tn], 0, 0, 0);
                acc[mt][tn] = __builtin_amdgcn_mfma_f32_16x16x32_bf16(ahi[mt], blo, acc[mt][tn], 0, 0, 0);
                acc[mt][tn] = __builtin_amdgcn_mfma_f32_16x16x32_bf16(alo[mt], bhi, acc[mt][tn], 0, 0, 0);
            }
        }
    }
    // epilogue 1: bias + relu -> H (bf16 hi/lo), wave-private rows
    #pragma unroll
    for (int mt = 0; mt < 2; ++mt)
        #pragma unroll
        for (int tn = 0; tn < 8; ++tn) {
            float bias = b1[tn * 16 + col];
            #pragma unroll
            for (int rr = 0; rr < 4; ++rr) {
                float v = fmaxf(acc[mt][tn][rr] + bias, 0.f);
                int m = wv * 32 + mt * 16 + quad * 4 + rr;
                unsigned short h = f2bf(v);
                Hhi[m][tn * 16 + col] = h;
                Hlo[m][tn * 16 + col] = f2bf(v - bf2f(h));
            }
        }

    // ---- layer 2: K = 128 (4 chunks) ----
    #pragma unroll
    for (int mt = 0; mt < 2; ++mt)
        #pragma unroll
        for (int t = 0; t < 8; ++t) acc[mt][t] = (f32x4){0.f, 0.f, 0.f, 0.f};
    {
        const int m0 = wv * 32 + col;
        #pragma unroll
        for (int ck = 0; ck < 4; ++ck) {
            short8 ahi[2], alo[2];
            #pragma unroll
            for (int mt = 0; mt < 2; ++mt) {
                ahi[mt] = *(const short8*)(&Hhi[m0 + mt * 16][ck * 32 + quad * 8]);
                alo[mt] = *(const short8*)(&Hlo[m0 + mt * 16][ck * 32 + quad * 8]);
            }
            const unsigned short* bh = w2h + (size_t)(ck * 8) * 512 + lane * 8;
            const unsigned short* bl = w2l + (size_t)(ck * 8) * 512 + lane * 8;
            #pragma unroll
            for (int tn = 0; tn < 8; ++tn) {
                short8 bhi = *(const short8*)(bh + tn * 512);
                short8 blo = *(const short8*)(bl + tn * 512);
                #pragma unroll
                for (int mt = 0; mt < 2; ++mt) {
                    acc[mt][tn] = __builtin_amdgcn_mfma_f32_16x16x32_bf16(ahi[mt], bhi, acc[mt][tn], 0, 0, 0);
                    acc[mt][tn] = __builtin_amdgcn_mfma_f32_16x16x32_bf16(ahi[mt], blo, acc[mt][tn], 0, 0, 0);
                    acc[mt][tn] = __builtin_amdgcn_mfma_f32_16x16x32_bf16(alo[mt], bhi, acc[mt][tn], 0, 0, 0);
                }
            }
        }
    }
    // epilogue 2: bias + relu -> H (reads of layer-2 A already done, in-order)
    #pragma unroll
    for (int mt = 0; mt < 2; ++mt)
        #pragma unroll
        for (int tn = 0; tn < 8; ++tn) {
            float bias = b2[tn * 16 + col];
            #pragma unroll
            for (int rr = 0; rr < 4; ++rr) {
                float v = fmaxf(acc[mt][tn][rr] + bias, 0.f);
                int m = wv * 32 + mt * 16 + quad * 4 + rr;
                unsigned short h = f2bf(v);
                Hhi[m][tn * 16 + col] = h;
                Hlo[m][tn * 16 + col] = f2bf(v - bf2f(h));
            }
        }

    // ---- layer 3: N = 64 (4 tiles), K = 128 ----
    f32x4 a3[2][4];
    #pragma unroll
    for (int mt = 0; mt < 2; ++mt)
        #pragma unroll
        for (int t = 0; t < 4; ++t) a3[mt][t] = (f32x4){0.f, 0.f, 0.f, 0.f};
    {
        const int m0 = wv * 32 + col;
        #pragma unroll
        for (int ck = 0; ck < 4; ++ck) {
            short8 ahi[2], alo[2];
            #pragma unroll
            for (int mt = 0; mt < 2; ++mt) {
                ahi[mt] = *(const short8*)(&Hhi[m0 + mt * 16][ck * 32 + quad * 8]);
                alo[mt] = *(const short8*)(&Hlo[m0 + mt * 16][ck * 32 + quad * 8]);
            }
            const unsigned short* bh = w3h + (size_t)(ck * 4) * 512 + lane * 8;
            const unsigned short* bl = w3l + (size_t)(ck * 4) * 512 + lane * 8;
            #pragma unroll
            for (int tn = 0; tn < 4; ++tn) {
                short8 bhi = *(const short8*)(bh + tn * 512);
                short8 blo = *(const short8*)(bl + tn * 512);
                #pragma unroll
                for (int mt = 0; mt < 2; ++mt) {
                    a3[mt][tn] = __builtin_amdgcn_mfma_f32_16x16x32_bf16(ahi[mt], bhi, a3[mt][tn], 0, 0, 0);
                    a3[mt][tn] = __builtin_amdgcn_mfma_f32_16x16x32_bf16(ahi[mt], blo, a3[mt][tn], 0, 0, 0);
                    a3[mt][tn] = __builtin_amdgcn_mfma_f32_16x16x32_bf16(alo[mt], bhi, a3[mt][tn], 0, 0, 0);
                }
            }
        }
    }
    // epilogue 3: bias + atomic scatter into nm[cols[edge]]
    #pragma unroll
    for (int mt = 0; mt < 2; ++mt) {
        int cc[4];
        #pragma unroll
        for (int rr = 0; rr < 4; ++rr)
            cc[rr] = cols[blockIdx.x * 64 + wv * 32 + mt * 16 + quad * 4 + rr];
        #pragma unroll
        for (int tn = 0; tn < 4; ++tn) {
            float bias = b3[tn * 16 + col];
            #pragma unroll
            for (int rr = 0; rr < 4; ++rr)
                atomicAdd(&nm[(size_t)cc[rr] * 64 + tn * 16 + col], a3[mt][tn][rr] + bias);
        }
    }
}

// ---------- GRU: 64 rows/block, 4 waves; transposed weights (unchanged) ----------
__global__ __launch_bounds__(256, 3)
void k_gru(float* __restrict__ nm,
           const float* __restrict__ wiht,   // [64][192] k-major
           const float* __restrict__ whht,   // [64][192] k-major
           const float* __restrict__ bih, const float* __restrict__ bhh,
           float* __restrict__ hst, int count)
{
    __shared__ float M[SDIM][64];
    __shared__ float Hs[SDIM][64];
    const int lane = threadIdx.x & 63;
    const int wv   = __builtin_amdgcn_readfirstlane(threadIdx.x >> 6);
    const int row0 = blockIdx.x * 64 + lane;
    const int row  = row0 < count ? row0 : count - 1;
    const float4* m4 = (const float4*)(nm + (size_t)row * 64);
    const float4* h4 = (const float4*)(hst + (size_t)row * 64);

    #pragma unroll
    for (int qq = 0; qq < 4; ++qq) {
        int q = 4 * wv + qq;
        float4 tm = m4[q], th = h4[q];
        M[4*q+0][lane] = tm.x; M[4*q+1][lane] = tm.y;
        M[4*q+2][lane] = tm.z; M[4*q+3][lane] = tm.w;
        Hs[4*q+0][lane] = th.x; Hs[4*q+1][lane] = th.y;
        Hs[4*q+2][lane] = th.z; Hs[4*q+3][lane] = th.w;
    }
    __syncthreads();

    const int j0 = 16 * wv;
    for (int jc = 0; jc < 16; jc += 4) {
        const int jb = j0 + jc;
        float air[4], aiz[4], ain[4], ahr[4], ahz[4], ahn[4];
        #pragma unroll
        for (int jj = 0; jj < 4; ++jj) {
            int j = jb + jj;
            air[jj] = bih[j];       aiz[jj] = bih[64 + j];  ain[jj] = bih[128 + j];
            ahr[jj] = bhh[j];       ahz[jj] = bhh[64 + j];  ahn[jj] = bhh[128 + j];
        }
        #pragma unroll 4
        for (int k = 0; k < SDIM; ++k) {
            float xk = M[k][lane], hk = Hs[k][lane];
            const float* wi = wiht + k * 192;
            const float* wh = whht + k * 192;
            #pragma unroll
            for (int jj = 0; jj < 4; ++jj) {
                int j = jb + jj;
                air[jj] = fmaf(wi[j],       xk, air[jj]);
                aiz[jj] = fmaf(wi[64 + j],  xk, aiz[jj]);
                ain[jj] = fmaf(wi[128 + j], xk, ain[jj]);
                ahr[jj] = fmaf(wh[j],       hk, ahr[jj]);
                ahz[jj] = fmaf(wh[64 + j],  hk, ahz[jj]);
                ahn[jj] = fmaf(wh[128 + j], hk, ahn[jj]);
            }
        }
        if (row0 < count) {
            float hn[4];
            #pragma unroll
            for (int jj = 0; jj < 4; ++jj) {
                int j = jb + jj;
                float r = sigm(air[jj] + ahr[jj]);
                float z = sigm(aiz[jj] + ahz[jj]);
                float t = tanh_f(ain[jj] + r * ahn[jj]);
                hn[jj] = (1.f - z) * t + z * Hs[j][lane];
            }
            *(float4*)(hst + (size_t)row * 64 + jb) =
                make_float4(hn[0], hn[1], hn[2], hn[3]);
        }
    }
    if (row0 < count) {
        float4* mo = (float4*)(nm + (size_t)row * 64);
        #pragma unroll
        for (int qq = 0; qq < 4; ++qq)
            mo[4 * wv + qq] = make_float4(0.f, 0.f, 0.f, 0.f);
    }
}

// ---------- readout (unchanged) ----------
__global__ __launch_bounds__(256, 3)
void k_readout(const float* __restrict__ vh,
               const float* __restrict__ w1t,    // [64][128] k-major
               const float* __restrict__ b1,
               const float* __restrict__ w2t,    // [128][128] k-major
               const float* __restrict__ b2,
               const float* __restrict__ w3, const float* __restrict__ b3,
               float* __restrict__ out)
{
    __shared__ float H[HRDIM][64];
    const int lane = threadIdx.x & 63;
    const int wv   = __builtin_amdgcn_readfirstlane(threadIdx.x >> 6);
    const int n0 = blockIdx.x * 64 + lane;
    const int n  = n0 < NN ? n0 : NN - 1;
    const float4* px = (const float4*)(vh + (size_t)n * 64);

    const int j1 = 32 * wv;
    float acc[32];
    #pragma unroll
    for (int j = 0; j < 32; ++j) acc[j] = b1[j1 + j];
    #pragma unroll 4
    for (int q = 0; q < 16; ++q) {
        float4 x4 = px[q];
        const float* wa = w1t + (4 * q + 0) * HRDIM + j1;
        const float* wb = w1t + (4 * q + 1) * HRDIM + j1;
        const float* wc = w1t + (4 * q + 2) * HRDIM + j1;
        const float* wd = w1t + (4 * q + 3) * HRDIM + j1;
        #pragma unroll
        for (int j = 0; j < 32; ++j) {
            acc[j] = fmaf(wa[j], x4.x, acc[j]);
            acc[j] = fmaf(wb[j], x4.y, acc[j]);
            acc[j] = fmaf(wc[j], x4.z, acc[j]);
            acc[j] = fmaf(wd[j], x4.w, acc[j]);
        }
    }
    #pragma unroll
    for (int j = 0; j < 32; ++j) H[j1 + j][lane] = fmaxf(acc[j], 0.f);
    __syncthreads();

    #pragma unroll
    for (int j = 0; j < 32; ++j) acc[j] = b2[j1 + j];
    #pragma unroll 4
    for (int k = 0; k < HRDIM; ++k) {
        float xk = H[k][lane];
        const float* wr = w2t + k * HRDIM + j1;
        #pragma unroll
        for (int j = 0; j < 32; ++j)
            acc[j] = fmaf(wr[j], xk, acc[j]);
    }
    __syncthreads();
    #pragma unroll
    for (int j = 0; j < 32; ++j) H[j1 + j][lane] = fmaxf(acc[j], 0.f);
    __syncthreads();

    if (wv == 0 && n0 < NN) {
        float l0 = b3[0], l1 = b3[1];
        #pragma unroll 8
        for (int k = 0; k < HRDIM; ++k) {
            float hk = H[k][lane];
            l0 = fmaf(w3[k],         hk, l0);
            l1 = fmaf(w3[HRDIM + k], hk, l1);
        }
        float mx = fmaxf(l0, l1);
        float e0 = __expf(l0 - mx), e1 = __expf(l1 - mx);
        float inv = 1.f / (e0 + e1);
        out[2 * n + 0] = e0 * inv;
        out[2 * n + 1] = e1 * inv;
    }
}

// ---------- host ----------
extern "C" void kernel_launch(void* const* d_in, const int* in_sizes, int n_in,
                              void* d_out, int out_size, void* d_ws, size_t ws_size,
                              hipStream_t stream)
{
    // ws layout (f32 units):
    //   var_h 640,000 | fac_h 5,120,000 | nm 5,120,000 | gru/ro transposed 73,728
    //   | packed MLP bf16 streams 90,112 f32-equiv  => total 11,043,840 f32 = 44.18 MB
    float* var_h = (float*)d_ws;
    float* fac_h = var_h + 640000;
    float* nm    = fac_h + 5120000;
    float* wts_t = nm + 5120000;                         // 73,728 f32
    unsigned short* pk = (unsigned short*)(wts_t + 73728); // 180,224 shorts

    const int*   f2v_row  = (const int*)d_in[0];
    const int*   f2v_col  = (const int*)d_in[1];
    const int*   v2f_row  = (const int*)d_in[2];
    const int*   v2f_col  = (const int*)d_in[3];
    const float* f2v_feat = (const float*)d_in[4];
    const float* v2f_feat = (const float*)d_in[5];
    const float* W[26];
    for (int j = 0; j < 26; ++j) W[j] = (const float*)d_in[6 + j];
    // W: 0..5 f2v MLP (w1,b1,w2,b2,w3,b3), 6..11 v2f MLP,
    //    12..15 gf GRU (wih,whh,bih,bhh), 16..19 gv GRU, 20..25 readout

    // transposed GRU/readout weights
    TArgs ta;
    float* T[NTR];
    {
        const float* src[NTR] = { W[12], W[13], W[16], W[17], W[20], W[22] };
        int R[NTR] = { 192, 192, 192, 192, HRDIM, HRDIM };
        int C[NTR] = { SDIM, SDIM, SDIM, SDIM, SDIM, HRDIM };
        size_t off = 0;
        for (int t = 0; t < NTR; ++t) {
            ta.src[t] = src[t]; ta.R[t] = R[t]; ta.C[t] = C[t];
            T[t] = wts_t + off; ta.dst[t] = T[t];
            off += (size_t)R[t] * C[t];
        }
    }
    // packed MLP B-frag streams: per direction w1(20480) w2(16384) w3(8192), hi+lo
    unsigned short* P[12]; // f2v: w1h,w1l,w2h,w2l,w3h,w3l ; v2f: same at +90112
    {
        size_t off = 0;
        int sz[3] = { 20480, 16384, 8192 };
        for (int d = 0; d < 2; ++d)
            for (int m = 0; m < 3; ++m) {
                P[d * 6 + m * 2 + 0] = pk + off; off += sz[m];
                P[d * 6 + m * 2 + 1] = pk + off; off += sz[m];
            }
    }
    PArgs pa;
    {
        const float* src[NPK] = { W[0], W[2], W[4], W[6], W[8], W[10] };
        int N[NPK]  = { HMDIM, HMDIM, SDIM,  HMDIM, HMDIM, SDIM };
        int K[NPK]  = { KIN,   HMDIM, HMDIM, KIN,   HMDIM, HMDIM };
        int CK[NPK] = { 5,     4,     4,     5,     4,     4 };
        int hiIdx[NPK] = { 0, 2, 4, 6, 8, 10 };
        for (int t = 0; t < NPK; ++t) {
            pa.src[t] = src[t]; pa.N[t] = N[t]; pa.K[t] = K[t]; pa.CK[t] = CK[t];
            pa.hi[t] = P[hiIdx[t]]; pa.lo[t] = P[hiIdx[t] + 1];
        }
    }
    k_transpose<<<NTR, 256, 0, stream>>>(ta);
    k_pack<<<NPK, 256, 0, stream>>>(pa);
    k_zero<<<512, 256, 0, stream>>>(var_h, 640000 + 5120000 + 5120000);

    for (int s = 0; s < NSTEPS; ++s) {
        // fac -> var messages into nm[node]; var GRU
        k_edge_mfma<<<NE / 64, 128, 0, stream>>>(
            fac_h, var_h, f2v_row, f2v_col, f2v_feat,
            P[0], P[1], P[2], P[3], P[4], P[5],
            W[1], W[3], W[5], nm);
        k_gru<<<(NN + 63) / 64, 256, 0, stream>>>(
            nm, T[0], T[1], W[14], W[15], var_h, NN);
        // var -> fac messages into nm[factor]; fac GRU
        k_edge_mfma<<<NE / 64, 128, 0, stream>>>(
            var_h, fac_h, v2f_row, v2f_col, v2f_feat,
            P[6], P[7], P[8], P[9], P[10], P[11],
            W[7], W[9], W[11], nm);
        k_gru<<<(NF + 63) / 64, 256, 0, stream>>>(
            nm, T[2], T[3], W[18], W[19], fac_h, NF);
    }
    k_readout<<<(NN + 63) / 64, 256, 0, stream>>>(
        var_h, T[4], W[21], T[5], W[23], W[24], W[25],
        (float*)d_out);
}

// Round 16
// 1419.474 us; speedup vs baseline: 21.0474x; 1.1923x over previous
//
#include <hip/hip_runtime.h>

// Problem constants (fixed by reference setup)
#define NN     10000      // variable nodes
#define NF     80000      // factors
#define NE     160000     // directed edges per direction
#define SDIM   64         // state dim
#define HMDIM  128        // hidden (message MLP)
#define HRDIM  128        // hidden (readout)
#define KIN    136        // 2*S + 8
#define NSTEPS 5

static_assert(NE % 64 == 0, "edge grid exact");

typedef __attribute__((ext_vector_type(8))) short short8;   // 8 bf16 = 4 VGPRs
typedef __attribute__((ext_vector_type(4))) float f32x4;    // MFMA C/D

// ---------- helpers ----------
static __device__ __forceinline__ float bf2f(unsigned short u) {
    return __uint_as_float(((unsigned int)u) << 16);
}
static __device__ __forceinline__ unsigned short f2bf(float f) {
    unsigned int u = __float_as_uint(f);
    u += 0x7fffu + ((u >> 16) & 1u);          // round-to-nearest-even
    return (unsigned short)(u >> 16);
}
static __device__ __forceinline__ float sigm(float x) {
    x = fminf(fmaxf(x, -30.f), 30.f);
    return 1.f / (1.f + __expf(-x));
}
static __device__ __forceinline__ float tanh_f(float x) {
    x = fminf(fmaxf(x, -15.f), 15.f);
    float t = __expf(2.f * x);
    return (t - 1.f) / (t + 1.f);
}
// split f32 -> bf16 hi + bf16 lo (x ~= hi + lo, ~16 mantissa bits kept)
static __device__ __forceinline__ void split8(const float* x, short8& hi, short8& lo) {
    #pragma unroll
    for (int i = 0; i < 8; ++i) {
        unsigned short h = f2bf(x[i]);
        hi[i] = (short)h;
        lo[i] = (short)f2bf(x[i] - bf2f(h));
    }
}
static __device__ __forceinline__ void f4pair_to8(float4 a, float4 b, float* xv) {
    xv[0]=a.x; xv[1]=a.y; xv[2]=a.z; xv[3]=a.w;
    xv[4]=b.x; xv[5]=b.y; xv[6]=b.z; xv[7]=b.w;
}

__global__ void k_zero(float* __restrict__ p, int n) {
    int i = blockIdx.x * blockDim.x + threadIdx.x;
    int stride = gridDim.x * blockDim.x;
    for (; i < n; i += stride) p[i] = 0.f;
}

// ---------- weight transpose for readout (dst[k][j] = src[j][k]) ----------
#define NTR 2
struct TArgs {
    const float* src[NTR];
    float*       dst[NTR];
    int          R[NTR];   // rows (output dim j)
    int          C[NTR];   // cols (input dim k)
};
__global__ void k_transpose(TArgs a) {
    const int b = blockIdx.x;
    const float* s = a.src[b];
    float* d = a.dst[b];
    const int R = a.R[b], C = a.C[b], n = R * C;
    for (int i = threadIdx.x; i < n; i += blockDim.x) {
        int r = i / C, c = i % C;
        d[c * R + r] = s[i];
    }
}

// ---------- pack weights into B-fragment streams (hi/lo bf16) ----------
// Stream element idx = ((ck*NT + tn)*64 + lane)*8 + j holds
// B[k = ck*32 + (lane>>4)*8 + j][n = tn*16 + (lane&15)] = w[n][k] (0 if k>=K).
#define NPK 10
struct PArgs {
    const float*    src[NPK];
    unsigned short* hi[NPK];
    unsigned short* lo[NPK];
    int             N[NPK], K[NPK], CK[NPK];
};
__global__ void k_pack(PArgs a) {
    const int b = blockIdx.x;
    const float* s = a.src[b];
    unsigned short* ph = a.hi[b];
    unsigned short* pl = a.lo[b];
    const int N = a.N[b], K = a.K[b], CK = a.CK[b];
    const int NT = N >> 4;
    const int total = NT * CK * 512;
    for (int i = threadIdx.x; i < total; i += blockDim.x) {
        int j    = i & 7;
        int ln   = (i >> 3) & 63;
        int tile = i >> 9;
        int tn   = tile % NT;
        int ck   = tile / NT;
        int k = ck * 32 + ((ln >> 4) * 8) + j;
        int n = tn * 16 + (ln & 15);
        float f = (k < K) ? s[n * K + k] : 0.f;
        unsigned short h = f2bf(f);
        ph[i] = h;
        pl[i] = f2bf(f - bf2f(h));
    }
}

// bias sums for GRU r/z gates: o[j] = bih[j] + bhh[j], j in [0,192)
__global__ void k_bsum(const float* bih0, const float* bhh0, float* o0,
                       const float* bih1, const float* bhh1, float* o1) {
    int i = threadIdx.x;
    if (i < 192) { o0[i] = bih0[i] + bhh0[i]; o1[i] = bih1[i] + bhh1[i]; }
}

// ---------- MFMA edge MLP + atomic scatter (M=32 per wave, hoisted gathers) ----------
// Block = 64 edges, 128 threads = 2 waves. Wave w owns edges [32w,32w+32)
// as TWO 16-row M-tiles. ALL random gathers (hrow/hcol/feat rows) are
// issued back-to-back at kernel entry (round-14 bottleneck: gathers
// interleaved in the ck-loop serialized ~10 L3 latencies). hi/lo split
// bf16: 3 MFMAs ~ fp32 accuracy. Acts in LDS, wave-private -> no barriers.
__global__ __launch_bounds__(128, 2)
void k_edge_mfma(const float* __restrict__ hrow, const float* __restrict__ hcol,
                 const int* __restrict__ rows, const int* __restrict__ cols,
                 const float* __restrict__ feat,
                 const unsigned short* __restrict__ w1h, const unsigned short* __restrict__ w1l,
                 const unsigned short* __restrict__ w2h, const unsigned short* __restrict__ w2l,
                 const unsigned short* __restrict__ w3h, const unsigned short* __restrict__ w3l,
                 const float* __restrict__ b1, const float* __restrict__ b2,
                 const float* __restrict__ b3,
                 float* __restrict__ nm)
{
    __shared__ unsigned short Hhi[64][136];   // stride 272B: conflict-light
    __shared__ unsigned short Hlo[64][136];   // 34 KB total
    const int lane = threadIdx.x & 63;
    const int wv   = threadIdx.x >> 6;        // 0..1
    const int quad = lane >> 4;               // 0..3
    const int col  = lane & 15;
    int r[2], c[2];
    {
        int e0 = blockIdx.x * 64 + wv * 32 + col;
        r[0] = rows[e0];      c[0] = cols[e0];
        r[1] = rows[e0 + 16]; c[1] = cols[e0 + 16];
    }

    // ---- hoisted gathers: 20 float4 loads issued together ----
    float4 gR[2][4], gC[2][4], gFr[2], gFc[2];
    #pragma unroll
    for (int mt = 0; mt < 2; ++mt) {
        const float4* pr = (const float4*)(hrow + (size_t)r[mt] * 64);
        const float4* pc = (const float4*)(hcol + (size_t)c[mt] * 64);
        gR[mt][0] = pr[quad * 2];     gR[mt][1] = pr[quad * 2 + 1];
        gR[mt][2] = pr[8 + quad * 2]; gR[mt][3] = pr[8 + quad * 2 + 1];
        gC[mt][0] = pc[quad * 2];     gC[mt][1] = pc[quad * 2 + 1];
        gC[mt][2] = pc[8 + quad * 2]; gC[mt][3] = pc[8 + quad * 2 + 1];
        gFr[mt] = *(const float4*)(feat + (size_t)r[mt] * 4);
        gFc[mt] = *(const float4*)(feat + (size_t)c[mt] * 4);
    }

    f32x4 acc[2][8];
    #pragma unroll
    for (int mt = 0; mt < 2; ++mt)
        #pragma unroll
        for (int t = 0; t < 8; ++t) acc[mt][t] = (f32x4){0.f, 0.f, 0.f, 0.f};

    // ---- layer 1: K = 136 padded to 160 (5 chunks of 32) ----
    #pragma unroll
    for (int ck = 0; ck < 5; ++ck) {
        short8 ahi[2], alo[2];
        #pragma unroll
        for (int mt = 0; mt < 2; ++mt) {
            float xv[8];
            if (ck < 2)      f4pair_to8(gR[mt][ck * 2], gR[mt][ck * 2 + 1], xv);
            else if (ck < 4) f4pair_to8(gC[mt][(ck - 2) * 2], gC[mt][(ck - 2) * 2 + 1], xv);
            else if (quad == 0) f4pair_to8(gFr[mt], gFc[mt], xv);
            else {
                for (int i = 0; i < 8; ++i) xv[i] = 0.f;
            }
            split8(xv, ahi[mt], alo[mt]);
        }
        const unsigned short* bh = w1h + (size_t)(ck * 8) * 512 + lane * 8;
        const unsigned short* bl = w1l + (size_t)(ck * 8) * 512 + lane * 8;
        #pragma unroll
        for (int tn = 0; tn < 8; ++tn) {
            short8 bhi = *(const short8*)(bh + tn * 512);
            short8 blo = *(const short8*)(bl + tn * 512);
            #pragma unroll
            for (int mt = 0; mt < 2; ++mt) {
                acc[mt][tn] = __builtin_amdgcn_mfma_f32_16x16x32_bf16(ahi[mt], bhi, acc[mt][tn], 0, 0, 0);
                acc[mt][tn] = __builtin_amdgcn_mfma_f32_16x16x32_bf16(ahi[mt], blo, acc[mt][tn], 0, 0, 0);
                acc[mt][tn] = __builtin_amdgcn_mfma_f32_16x16x32_bf16(alo[mt], bhi, acc[mt][tn], 0, 0, 0);
            }
        }
    }
    // epilogue 1: bias + relu -> H (bf16 hi/lo), wave-private rows
    #pragma unroll
    for (int mt = 0; mt < 2; ++mt)
        #pragma unroll
        for (int tn = 0; tn < 8; ++tn) {
            float bias = b1[tn * 16 + col];
            #pragma unroll
            for (int rr = 0; rr < 4; ++rr) {
                float v = fmaxf(acc[mt][tn][rr] + bias, 0.f);
                int m = wv * 32 + mt * 16 + quad * 4 + rr;
                unsigned short h = f2bf(v);
                Hhi[m][tn * 16 + col] = h;
                Hlo[m][tn * 16 + col] = f2bf(v - bf2f(h));
            }
        }

    // ---- layer 2: K = 128 (4 chunks) ----
    #pragma unroll
    for (int mt = 0; mt < 2; ++mt)
        #pragma unroll
        for (int t = 0; t < 8; ++t) acc[mt][t] = (f32x4){0.f, 0.f, 0.f, 0.f};
    {
        const int m0 = wv * 32 + col;
        #pragma unroll
        for (int ck = 0; ck < 4; ++ck) {
            short8 ahi[2], alo[2];
            #pragma unroll
            for (int mt = 0; mt < 2; ++mt) {
                ahi[mt] = *(const short8*)(&Hhi[m0 + mt * 16][ck * 32 + quad * 8]);
                alo[mt] = *(const short8*)(&Hlo[m0 + mt * 16][ck * 32 + quad * 8]);
            }
            const unsigned short* bh = w2h + (size_t)(ck * 8) * 512 + lane * 8;
            const unsigned short* bl = w2l + (size_t)(ck * 8) * 512 + lane * 8;
            #pragma unroll
            for (int tn = 0; tn < 8; ++tn) {
                short8 bhi = *(const short8*)(bh + tn * 512);
                short8 blo = *(const short8*)(bl + tn * 512);
                #pragma unroll
                for (int mt = 0; mt < 2; ++mt) {
                    acc[mt][tn] = __builtin_amdgcn_mfma_f32_16x16x32_bf16(ahi[mt], bhi, acc[mt][tn], 0, 0, 0);
                    acc[mt][tn] = __builtin_amdgcn_mfma_f32_16x16x32_bf16(ahi[mt], blo, acc[mt][tn], 0, 0, 0);
                    acc[mt][tn] = __builtin_amdgcn_mfma_f32_16x16x32_bf16(alo[mt], bhi, acc[mt][tn], 0, 0, 0);
                }
            }
        }
    }
    // epilogue 2
    #pragma unroll
    for (int mt = 0; mt < 2; ++mt)
        #pragma unroll
        for (int tn = 0; tn < 8; ++tn) {
            float bias = b2[tn * 16 + col];
            #pragma unroll
            for (int rr = 0; rr < 4; ++rr) {
                float v = fmaxf(acc[mt][tn][rr] + bias, 0.f);
                int m = wv * 32 + mt * 16 + quad * 4 + rr;
                unsigned short h = f2bf(v);
                Hhi[m][tn * 16 + col] = h;
                Hlo[m][tn * 16 + col] = f2bf(v - bf2f(h));
            }
        }

    // ---- layer 3: N = 64 (4 tiles), K = 128 ----
    f32x4 a3[2][4];
    #pragma unroll
    for (int mt = 0; mt < 2; ++mt)
        #pragma unroll
        for (int t = 0; t < 4; ++t) a3[mt][t] = (f32x4){0.f, 0.f, 0.f, 0.f};
    {
        const int m0 = wv * 32 + col;
        #pragma unroll
        for (int ck = 0; ck < 4; ++ck) {
            short8 ahi[2], alo[2];
            #pragma unroll
            for (int mt = 0; mt < 2; ++mt) {
                ahi[mt] = *(const short8*)(&Hhi[m0 + mt * 16][ck * 32 + quad * 8]);
                alo[mt] = *(const short8*)(&Hlo[m0 + mt * 16][ck * 32 + quad * 8]);
            }
            const unsigned short* bh = w3h + (size_t)(ck * 4) * 512 + lane * 8;
            const unsigned short* bl = w3l + (size_t)(ck * 4) * 512 + lane * 8;
            #pragma unroll
            for (int tn = 0; tn < 4; ++tn) {
                short8 bhi = *(const short8*)(bh + tn * 512);
                short8 blo = *(const short8*)(bl + tn * 512);
                #pragma unroll
                for (int mt = 0; mt < 2; ++mt) {
                    a3[mt][tn] = __builtin_amdgcn_mfma_f32_16x16x32_bf16(ahi[mt], bhi, a3[mt][tn], 0, 0, 0);
                    a3[mt][tn] = __builtin_amdgcn_mfma_f32_16x16x32_bf16(ahi[mt], blo, a3[mt][tn], 0, 0, 0);
                    a3[mt][tn] = __builtin_amdgcn_mfma_f32_16x16x32_bf16(alo[mt], bhi, a3[mt][tn], 0, 0, 0);
                }
            }
        }
    }
    // epilogue 3: bias + atomic scatter into nm[cols[edge]]
    #pragma unroll
    for (int mt = 0; mt < 2; ++mt) {
        int cc[4];
        #pragma unroll
        for (int rr = 0; rr < 4; ++rr)
            cc[rr] = cols[blockIdx.x * 64 + wv * 32 + mt * 16 + quad * 4 + rr];
        #pragma unroll
        for (int tn = 0; tn < 4; ++tn) {
            float bias = b3[tn * 16 + col];
            #pragma unroll
            for (int rr = 0; rr < 4; ++rr)
                atomicAdd(&nm[(size_t)cc[rr] * 64 + tn * 16 + col], a3[mt][tn][rr] + bias);
        }
    }
}

// ---------- MFMA GRU: h = GRU(nm, h) ----------
// Block = 64 rows, 128 threads = 2 waves; wave w owns rows [32w,+32) as two
// 16-row M-tiles. r/z gates: acc = nm*wih_rz^T + h*whh_rz^T (MFMA
// accumulates across both matmuls); n gate: gi_n, gh_n kept separate.
// h staged in LDS (stride 68) for the D-layout epilogue. Zeroes nm rows.
__global__ __launch_bounds__(128, 2)
void k_gru_mfma(float* __restrict__ nm,
                const unsigned short* __restrict__ wih_h, const unsigned short* __restrict__ wih_l,
                const unsigned short* __restrict__ whh_h, const unsigned short* __restrict__ whh_l,
                const float* __restrict__ bsum,          // bih+bhh [192]
                const float* __restrict__ bih, const float* __restrict__ bhh,
                float* __restrict__ hst, int count)
{
    __shared__ float Hs[64][68];              // 17.4 KB, stride-68 conflict-free
    const int lane = threadIdx.x & 63;
    const int wv   = threadIdx.x >> 6;        // 0..1
    const int quad = lane >> 4;
    const int col  = lane & 15;
    const int base = blockIdx.x * 64;

    // A-frag loads (rows = wv*32 + mt*16 + col), clamped
    float4 am[2][4], ah[2][4];
    #pragma unroll
    for (int mt = 0; mt < 2; ++mt) {
        int ra = base + wv * 32 + mt * 16 + col;
        ra = ra < count ? ra : count - 1;
        const float4* pm = (const float4*)(nm + (size_t)ra * 64);
        const float4* ph = (const float4*)(hst + (size_t)ra * 64);
        am[mt][0] = pm[quad * 2];     am[mt][1] = pm[quad * 2 + 1];
        am[mt][2] = pm[8 + quad * 2]; am[mt][3] = pm[8 + quad * 2 + 1];
        ah[mt][0] = ph[quad * 2];     ah[mt][1] = ph[quad * 2 + 1];
        ah[mt][2] = ph[8 + quad * 2]; ah[mt][3] = ph[8 + quad * 2 + 1];
    }
    // stage h into LDS (wave-private rows; in-wave program order suffices)
    #pragma unroll
    for (int mt = 0; mt < 2; ++mt) {
        int rowl = wv * 32 + mt * 16 + col;
        *(float4*)(&Hs[rowl][quad * 8])      = ah[mt][0];
        *(float4*)(&Hs[rowl][quad * 8 + 4])  = ah[mt][1];
        *(float4*)(&Hs[rowl][32 + quad * 8])     = ah[mt][2];
        *(float4*)(&Hs[rowl][32 + quad * 8 + 4]) = ah[mt][3];
    }

    f32x4 rz[2][8], ni[2][4], nh[2][4];
    #pragma unroll
    for (int mt = 0; mt < 2; ++mt) {
        #pragma unroll
        for (int t = 0; t < 8; ++t) rz[mt][t] = (f32x4){0.f, 0.f, 0.f, 0.f};
        #pragma unroll
        for (int t = 0; t < 4; ++t) {
            ni[mt][t] = (f32x4){0.f, 0.f, 0.f, 0.f};
            nh[mt][t] = (f32x4){0.f, 0.f, 0.f, 0.f};
        }
    }

    #pragma unroll
    for (int ck = 0; ck < 2; ++ck) {
        short8 mhi[2], mlo[2], hhi[2], hlo[2];
        #pragma unroll
        for (int mt = 0; mt < 2; ++mt) {
            float xv[8];
            f4pair_to8(am[mt][ck * 2], am[mt][ck * 2 + 1], xv);
            split8(xv, mhi[mt], mlo[mt]);
            f4pair_to8(ah[mt][ck * 2], ah[mt][ck * 2 + 1], xv);
            split8(xv, hhi[mt], hlo[mt]);
        }
        const unsigned short* ih = wih_h + (size_t)(ck * 12) * 512 + lane * 8;
        const unsigned short* il = wih_l + (size_t)(ck * 12) * 512 + lane * 8;
        const unsigned short* hh = whh_h + (size_t)(ck * 12) * 512 + lane * 8;
        const unsigned short* hl = whh_l + (size_t)(ck * 12) * 512 + lane * 8;
        // r/z gates: tn 0..7, both matmuls into the same acc
        #pragma unroll
        for (int tn = 0; tn < 8; ++tn) {
            short8 bihh = *(const short8*)(ih + tn * 512);
            short8 bihl = *(const short8*)(il + tn * 512);
            short8 bhhh = *(const short8*)(hh + tn * 512);
            short8 bhhl = *(const short8*)(hl + tn * 512);
            #pragma unroll
            for (int mt = 0; mt < 2; ++mt) {
                rz[mt][tn] = __builtin_amdgcn_mfma_f32_16x16x32_bf16(mhi[mt], bihh, rz[mt][tn], 0, 0, 0);
                rz[mt][tn] = __builtin_amdgcn_mfma_f32_16x16x32_bf16(mhi[mt], bihl, rz[mt][tn], 0, 0, 0);
                rz[mt][tn] = __builtin_amdgcn_mfma_f32_16x16x32_bf16(mlo[mt], bihh, rz[mt][tn], 0, 0, 0);
                rz[mt][tn] = __builtin_amdgcn_mfma_f32_16x16x32_bf16(hhi[mt], bhhh, rz[mt][tn], 0, 0, 0);
                rz[mt][tn] = __builtin_amdgcn_mfma_f32_16x16x32_bf16(hhi[mt], bhhl, rz[mt][tn], 0, 0, 0);
                rz[mt][tn] = __builtin_amdgcn_mfma_f32_16x16x32_bf16(hlo[mt], bhhh, rz[mt][tn], 0, 0, 0);
            }
        }
        // n gate: tn 8..11, gi_n and gh_n separate
        #pragma unroll
        for (int tn = 8; tn < 12; ++tn) {
            short8 bihh = *(const short8*)(ih + tn * 512);
            short8 bihl = *(const short8*)(il + tn * 512);
            short8 bhhh = *(const short8*)(hh + tn * 512);
            short8 bhhl = *(const short8*)(hl + tn * 512);
            #pragma unroll
            for (int mt = 0; mt < 2; ++mt) {
                ni[mt][tn - 8] = __builtin_amdgcn_mfma_f32_16x16x32_bf16(mhi[mt], bihh, ni[mt][tn - 8], 0, 0, 0);
                ni[mt][tn - 8] = __builtin_amdgcn_mfma_f32_16x16x32_bf16(mhi[mt], bihl, ni[mt][tn - 8], 0, 0, 0);
                ni[mt][tn - 8] = __builtin_amdgcn_mfma_f32_16x16x32_bf16(mlo[mt], bihh, ni[mt][tn - 8], 0, 0, 0);
                nh[mt][tn - 8] = __builtin_amdgcn_mfma_f32_16x16x32_bf16(hhi[mt], bhhh, nh[mt][tn - 8], 0, 0, 0);
                nh[mt][tn - 8] = __builtin_amdgcn_mfma_f32_16x16x32_bf16(hhi[mt], bhhl, nh[mt][tn - 8], 0, 0, 0);
                nh[mt][tn - 8] = __builtin_amdgcn_mfma_f32_16x16x32_bf16(hlo[mt], bhhh, nh[mt][tn - 8], 0, 0, 0);
            }
        }
    }

    // epilogue: gates + state update + nm zeroing (D layout: row=quad*4+rr, col)
    #pragma unroll
    for (int mt = 0; mt < 2; ++mt) {
        #pragma unroll
        for (int rr = 0; rr < 4; ++rr) {
            int rowl = wv * 32 + mt * 16 + quad * 4 + rr;
            int grow = base + rowl;
            bool ok = grow < count;
            #pragma unroll
            for (int t = 0; t < 4; ++t) {
                int g = t * 16 + col;
                float rv = sigm(rz[mt][t][rr] + bsum[g]);
                float zv = sigm(rz[mt][4 + t][rr] + bsum[64 + g]);
                float nv = tanh_f(ni[mt][t][rr] + bih[128 + g]
                                  + rv * (nh[mt][t][rr] + bhh[128 + g]));
                if (ok) {
                    float ho = Hs[rowl][g];
                    hst[(size_t)grow * 64 + g] = (1.f - zv) * nv + zv * ho;
                    nm[(size_t)grow * 64 + g] = 0.f;
                }
            }
        }
    }
}

// ---------- readout (unchanged) ----------
__global__ __launch_bounds__(256, 3)
void k_readout(const float* __restrict__ vh,
               const float* __restrict__ w1t,    // [64][128] k-major
               const float* __restrict__ b1,
               const float* __restrict__ w2t,    // [128][128] k-major
               const float* __restrict__ b2,
               const float* __restrict__ w3, const float* __restrict__ b3,
               float* __restrict__ out)
{
    __shared__ float H[HRDIM][64];
    const int lane = threadIdx.x & 63;
    const int wv   = __builtin_amdgcn_readfirstlane(threadIdx.x >> 6);
    const int n0 = blockIdx.x * 64 + lane;
    const int n  = n0 < NN ? n0 : NN - 1;
    const float4* px = (const float4*)(vh + (size_t)n * 64);

    const int j1 = 32 * wv;
    float acc[32];
    #pragma unroll
    for (int j = 0; j < 32; ++j) acc[j] = b1[j1 + j];
    #pragma unroll 4
    for (int q = 0; q < 16; ++q) {
        float4 x4 = px[q];
        const float* wa = w1t + (4 * q + 0) * HRDIM + j1;
        const float* wb = w1t + (4 * q + 1) * HRDIM + j1;
        const float* wc = w1t + (4 * q + 2) * HRDIM + j1;
        const float* wd = w1t + (4 * q + 3) * HRDIM + j1;
        #pragma unroll
        for (int j = 0; j < 32; ++j) {
            acc[j] = fmaf(wa[j], x4.x, acc[j]);
            acc[j] = fmaf(wb[j], x4.y, acc[j]);
            acc[j] = fmaf(wc[j], x4.z, acc[j]);
            acc[j] = fmaf(wd[j], x4.w, acc[j]);
        }
    }
    #pragma unroll
    for (int j = 0; j < 32; ++j) H[j1 + j][lane] = fmaxf(acc[j], 0.f);
    __syncthreads();

    #pragma unroll
    for (int j = 0; j < 32; ++j) acc[j] = b2[j1 + j];
    #pragma unroll 4
    for (int k = 0; k < HRDIM; ++k) {
        float xk = H[k][lane];
        const float* wr = w2t + k * HRDIM + j1;
        #pragma unroll
        for (int j = 0; j < 32; ++j)
            acc[j] = fmaf(wr[j], xk, acc[j]);
    }
    __syncthreads();
    #pragma unroll
    for (int j = 0; j < 32; ++j) H[j1 + j][lane] = fmaxf(acc[j], 0.f);
    __syncthreads();

    if (wv == 0 && n0 < NN) {
        float l0 = b3[0], l1 = b3[1];
        #pragma unroll 8
        for (int k = 0; k < HRDIM; ++k) {
            float hk = H[k][lane];
            l0 = fmaf(w3[k],         hk, l0);
            l1 = fmaf(w3[HRDIM + k], hk, l1);
        }
        float mx = fmaxf(l0, l1);
        float e0 = __expf(l0 - mx), e1 = __expf(l1 - mx);
        float inv = 1.f / (e0 + e1);
        out[2 * n + 0] = e0 * inv;
        out[2 * n + 1] = e1 * inv;
    }
}

// ---------- host ----------
extern "C" void kernel_launch(void* const* d_in, const int* in_sizes, int n_in,
                              void* d_out, int out_size, void* d_ws, size_t ws_size,
                              hipStream_t stream)
{
    // ws (f32 units): states 10,880,000 | ro_t 24,576 | bsum 384 | packed 139,264
    // total 11,044,224 f32 = 44.18 MB
    float* var_h = (float*)d_ws;
    float* fac_h = var_h + 640000;
    float* nm    = fac_h + 5120000;
    float* ro_t  = nm + 5120000;            // 24,576 f32
    float* bsum  = ro_t + 24576;            // 384 f32 (2 x 192)
    unsigned short* pk = (unsigned short*)(bsum + 384); // 278,528 shorts

    const int*   f2v_row  = (const int*)d_in[0];
    const int*   f2v_col  = (const int*)d_in[1];
    const int*   v2f_row  = (const int*)d_in[2];
    const int*   v2f_col  = (const int*)d_in[3];
    const float* f2v_feat = (const float*)d_in[4];
    const float* v2f_feat = (const float*)d_in[5];
    const float* W[26];
    for (int j = 0; j < 26; ++j) W[j] = (const float*)d_in[6 + j];
    // W: 0..5 f2v MLP (w1,b1,w2,b2,w3,b3), 6..11 v2f MLP,
    //    12..15 gf GRU (wih,whh,bih,bhh), 16..19 gv GRU, 20..25 readout

    // readout transposes
    TArgs ta;
    float* T[NTR];
    {
        const float* src[NTR] = { W[20], W[22] };
        int R[NTR] = { HRDIM, HRDIM };
        int C[NTR] = { SDIM, HRDIM };
        size_t off = 0;
        for (int t = 0; t < NTR; ++t) {
            ta.src[t] = src[t]; ta.R[t] = R[t]; ta.C[t] = C[t];
            T[t] = ro_t + off; ta.dst[t] = T[t];
            off += (size_t)R[t] * C[t];
        }
    }
    // packed B-frag streams
    unsigned short* P[12];  // edge: f2v w1h,w1l,w2h,w2l,w3h,w3l ; v2f same
    unsigned short* G[8];   // gf_wih h/l, gf_whh h/l, gv_wih h/l, gv_whh h/l
    {
        size_t off = 0;
        int esz[3] = { 20480, 16384, 8192 };
        for (int d = 0; d < 2; ++d)
            for (int m = 0; m < 3; ++m) {
                P[d * 6 + m * 2 + 0] = pk + off; off += esz[m];
                P[d * 6 + m * 2 + 1] = pk + off; off += esz[m];
            }
        for (int t = 0; t < 8; ++t) { G[t] = pk + off; off += 12288; }
    }
    PArgs pa;
    {
        const float* src[NPK] = { W[0], W[2], W[4], W[6], W[8], W[10],
                                  W[12], W[13], W[16], W[17] };
        int N[NPK]  = { HMDIM, HMDIM, SDIM,  HMDIM, HMDIM, SDIM,  192, 192, 192, 192 };
        int K[NPK]  = { KIN,   HMDIM, HMDIM, KIN,   HMDIM, HMDIM, SDIM, SDIM, SDIM, SDIM };
        int CK[NPK] = { 5,     4,     4,     5,     4,     4,     2,   2,   2,   2 };
        unsigned short* hi[NPK] = { P[0], P[2], P[4], P[6], P[8], P[10],
                                    G[0], G[2], G[4], G[6] };
        unsigned short* lo[NPK] = { P[1], P[3], P[5], P[7], P[9], P[11],
                                    G[1], G[3], G[5], G[7] };
        for (int t = 0; t < NPK; ++t) {
            pa.src[t] = src[t]; pa.N[t] = N[t]; pa.K[t] = K[t]; pa.CK[t] = CK[t];
            pa.hi[t] = hi[t];   pa.lo[t] = lo[t];
        }
    }
    k_transpose<<<NTR, 256, 0, stream>>>(ta);
    k_pack<<<NPK, 256, 0, stream>>>(pa);
    k_bsum<<<1, 256, 0, stream>>>(W[14], W[15], bsum, W[18], W[19], bsum + 192);
    k_zero<<<512, 256, 0, stream>>>(var_h, 640000 + 5120000 + 5120000);

    for (int s = 0; s < NSTEPS; ++s) {
        // fac -> var messages into nm[node]; var GRU (gf weights)
        k_edge_mfma<<<NE / 64, 128, 0, stream>>>(
            fac_h, var_h, f2v_row, f2v_col, f2v_feat,
            P[0], P[1], P[2], P[3], P[4], P[5],
            W[1], W[3], W[5], nm);
        k_gru_mfma<<<(NN + 63) / 64, 128, 0, stream>>>(
            nm, G[0], G[1], G[2], G[3], bsum, W[14], W[15], var_h, NN);
        // var -> fac messages into nm[factor]; fac GRU (gv weights)
        k_edge_mfma<<<NE / 64, 128, 0, stream>>>(
            var_h, fac_h, v2f_row, v2f_col, v2f_feat,
            P[6], P[7], P[8], P[9], P[10], P[11],
            W[7], W[9], W[11], nm);
        k_gru_mfma<<<(NF + 63) / 64, 128, 0, stream>>>(
            nm, G[4], G[5], G[6], G[7], bsum + 192, W[18], W[19], fac_h, NF);
    }
    k_readout<<<(NN + 63) / 64, 256, 0, stream>>>(
        var_h, T[0], W[21], T[1], W[23], W[24], W[25],
        (float*)d_out);
}